// Round 1
// baseline (2053.398 us; speedup 1.0000x reference)
//
#include <hip/hip_runtime.h>

// Problem constants (fixed by the reference)
#define B_ 64
#define N_ 207
#define T_ 24
#define D_ 128
#define H_ 8
#define MROWS (B_*N_*T_)             // 317952 (divisible by 64)
#define SELEMS ((size_t)MROWS * D_)  // 40697856
#define NBLK_BN 1024
#define EPS_ 1e-5f

// ws layout (bytes): gcn bf16 [SELEMS] | attn bf16 [SELEMS] | psum f32[1024*128]
// | psq f32[1024*128] | mean f32[128] | invstd f32[128]  => ~156.3 MiB total.

__device__ __forceinline__ float bfu2f(unsigned short u) {
  return __uint_as_float(((unsigned int)u) << 16);
}
__device__ __forceinline__ unsigned short f2bfu(float f) {
  unsigned int x = __float_as_uint(f);
  return (unsigned short)((x + 0x7fffu + ((x >> 16) & 1u)) >> 16);  // RNE
}

// ---------------------------------------------------------------------------
// Kernel 1: fused GCN branch.
// agg[b,m,t,:] = sum_n matrix[b,t,n,m] * hidden[b,n,t,:]   (per (b,t): M^T @ X)
// gcn[b,m,t,:] = agg @ Wgcn^T + bgcn   -> bf16
// Block: 256 thr, tile m0..m0+63 x 128 cols, K-loop over n in chunks of 16.
// ---------------------------------------------------------------------------
__global__ __launch_bounds__(256) void k_gcn(
    const float* __restrict__ hidden, const float* __restrict__ matrix,
    const float* __restrict__ Wgcn, const float* __restrict__ bgcn,
    unsigned short* __restrict__ gcn)
{
  __shared__ float smem[3136 + 64*132];   // 46.3 KB -> 3 blocks/CU
  float* Ms  = smem;            // [16][64]   phase-1 matrix tile
  float* Hs  = smem + 1024;     // [16][132]  phase-1 hidden tile (pad 132)
  float* Agg = smem + 3136;     // [64][132]  agg tile
  float* Ws  = smem;            // [16][128]  phase-2 W tile (reuses Ms/Hs)

  const int tid = threadIdx.x;
  const int tx = tid & 15, ty = tid >> 4;        // 16 x 16
  const int m0 = blockIdx.x * 64;
  const int bt = (int)blockIdx.y;
  const int b = bt / T_, t = bt % T_;

  float acc[4][8];
  #pragma unroll
  for (int i = 0; i < 4; i++)
    #pragma unroll
    for (int j = 0; j < 8; j++) acc[i][j] = 0.f;

  const int kk = ty;        // chunk-row this thread loads
  const int hc = tx * 8;    // Hs col base for loads

  for (int n0 = 0; n0 < N_; n0 += 16) {
    const int n = n0 + kk;
    const bool nok = (n < N_);
    const int nsafe = nok ? n : 0;
    // stage loads into regs
    float mv[4];
    const float* mrow = matrix + ((size_t)(b*T_ + t)*N_ + nsafe)*N_ + m0;
    #pragma unroll
    for (int i = 0; i < 4; i++) {
      const int mm = tx + 16*i;
      mv[i] = (nok && (m0 + mm) < N_) ? mrow[mm] : 0.f;
    }
    float4 h0 = make_float4(0.f,0.f,0.f,0.f), h1 = make_float4(0.f,0.f,0.f,0.f);
    if (nok) {
      const float* hrow = hidden + (((size_t)b*N_ + n)*T_ + t)*D_ + hc;
      h0 = *(const float4*)(hrow);
      h1 = *(const float4*)(hrow + 4);
    }
    __syncthreads();   // protect previous chunk's compute
    #pragma unroll
    for (int i = 0; i < 4; i++) Ms[kk*64 + tx + 16*i] = mv[i];
    *(float4*)&Hs[kk*132 + hc]     = h0;
    *(float4*)&Hs[kk*132 + hc + 4] = h1;
    __syncthreads();
    #pragma unroll
    for (int k2 = 0; k2 < 16; k2++) {
      float a[4];
      #pragma unroll
      for (int i = 0; i < 4; i++) a[i] = Ms[k2*64 + ty*4 + i];
      const float4 hlo = *(const float4*)&Hs[k2*132 + tx*4];
      const float4 hhi = *(const float4*)&Hs[k2*132 + 64 + tx*4];
      const float hv[8] = {hlo.x,hlo.y,hlo.z,hlo.w,hhi.x,hhi.y,hhi.z,hhi.w};
      #pragma unroll
      for (int i = 0; i < 4; i++)
        #pragma unroll
        for (int j = 0; j < 8; j++) acc[i][j] += a[i]*hv[j];
    }
  }

  // stage agg tile to LDS (distinct region; made visible by next barrier)
  #pragma unroll
  for (int i = 0; i < 4; i++) {
    *(float4*)&Agg[(ty*4+i)*132 + tx*4]      = make_float4(acc[i][0],acc[i][1],acc[i][2],acc[i][3]);
    *(float4*)&Agg[(ty*4+i)*132 + 64 + tx*4] = make_float4(acc[i][4],acc[i][5],acc[i][6],acc[i][7]);
  }

  // phase 2: gcn = Agg @ Wgcn^T
  float acc2[4][8];
  #pragma unroll
  for (int i = 0; i < 4; i++)
    #pragma unroll
    for (int j = 0; j < 8; j++) acc2[i][j] = 0.f;

  const int jW = tid & 127, cc0 = (tid >> 7) * 8;
  for (int c0 = 0; c0 < 128; c0 += 16) {
    const float* wrow = Wgcn + (size_t)jW*D_ + c0 + cc0;
    const float4 w0 = *(const float4*)wrow;
    const float4 w1 = *(const float4*)(wrow + 4);
    __syncthreads();   // protect phase-1 Ms/Hs reads + prior chunk; Agg now visible
    Ws[(cc0+0)*128 + jW] = w0.x;
    Ws[(cc0+1)*128 + jW] = w0.y;
    Ws[(cc0+2)*128 + jW] = w0.z;
    Ws[(cc0+3)*128 + jW] = w0.w;
    Ws[(cc0+4)*128 + jW] = w1.x;
    Ws[(cc0+5)*128 + jW] = w1.y;
    Ws[(cc0+6)*128 + jW] = w1.z;
    Ws[(cc0+7)*128 + jW] = w1.w;
    __syncthreads();
    #pragma unroll
    for (int cc = 0; cc < 16; cc++) {
      float a[4];
      #pragma unroll
      for (int i = 0; i < 4; i++) a[i] = Agg[(ty*4+i)*132 + c0 + cc];
      const float4 wlo = *(const float4*)&Ws[cc*128 + tx*4];
      const float4 whi = *(const float4*)&Ws[cc*128 + 64 + tx*4];
      const float wv[8] = {wlo.x,wlo.y,wlo.z,wlo.w,whi.x,whi.y,whi.z,whi.w};
      #pragma unroll
      for (int i = 0; i < 4; i++)
        #pragma unroll
        for (int j = 0; j < 8; j++) acc2[i][j] += a[i]*wv[j];
    }
  }

  const float4 blo = *(const float4*)(bgcn + tx*4);
  const float4 bhi = *(const float4*)(bgcn + 64 + tx*4);
  const float bv[8] = {blo.x,blo.y,blo.z,blo.w,bhi.x,bhi.y,bhi.z,bhi.w};
  #pragma unroll
  for (int i = 0; i < 4; i++) {
    const int m = m0 + ty*4 + i;
    if (m < N_) {
      unsigned short* orow = gcn + (((size_t)b*N_ + m)*T_ + t)*D_;
      ushort4 ulo, uhi;
      ulo.x = f2bfu(acc2[i][0] + bv[0]); ulo.y = f2bfu(acc2[i][1] + bv[1]);
      ulo.z = f2bfu(acc2[i][2] + bv[2]); ulo.w = f2bfu(acc2[i][3] + bv[3]);
      uhi.x = f2bfu(acc2[i][4] + bv[4]); uhi.y = f2bfu(acc2[i][5] + bv[5]);
      uhi.z = f2bfu(acc2[i][6] + bv[6]); uhi.w = f2bfu(acc2[i][7] + bv[7]);
      *(ushort4*)(orow + tx*4)      = ulo;
      *(ushort4*)(orow + 64 + tx*4) = uhi;
    }
  }
}

// ---------------------------------------------------------------------------
// Kernel 2: fused QKV + causal attention + Wo, one block per (b,n).
// ---------------------------------------------------------------------------
// Out[r][j] = sum_c Xs[r][c]*W[j][c] + bias[j], r in {ty, 16+ty} (rows >=24 are
// zero-padded), written either to LDS (132-stride) or global bf16 (128-stride).
__device__ __forceinline__ void proj24(
    const float* __restrict__ Xs, float* __restrict__ Ws,
    const float* __restrict__ W, const float* __restrict__ bias,
    float* __restrict__ OutLds, unsigned short* __restrict__ outG, int tid)
{
  const int tx = tid & 15, ty = tid >> 4;
  const int jW = tid & 127, cc0 = (tid >> 7) * 8;
  float acc0[8], acc1[8];
  #pragma unroll
  for (int j = 0; j < 8; j++) { acc0[j] = 0.f; acc1[j] = 0.f; }

  for (int c0 = 0; c0 < 128; c0 += 16) {
    const float* wrow = W + (size_t)jW*128 + c0 + cc0;
    const float4 w0 = *(const float4*)wrow;
    const float4 w1 = *(const float4*)(wrow + 4);
    __syncthreads();
    Ws[(cc0+0)*128 + jW] = w0.x;
    Ws[(cc0+1)*128 + jW] = w0.y;
    Ws[(cc0+2)*128 + jW] = w0.z;
    Ws[(cc0+3)*128 + jW] = w0.w;
    Ws[(cc0+4)*128 + jW] = w1.x;
    Ws[(cc0+5)*128 + jW] = w1.y;
    Ws[(cc0+6)*128 + jW] = w1.z;
    Ws[(cc0+7)*128 + jW] = w1.w;
    __syncthreads();
    #pragma unroll
    for (int cc = 0; cc < 16; cc++) {
      const float x0 = Xs[ty*132 + c0 + cc];
      const float x1 = Xs[(16+ty)*132 + c0 + cc];
      const float4 wlo = *(const float4*)&Ws[cc*128 + tx*4];
      const float4 whi = *(const float4*)&Ws[cc*128 + 64 + tx*4];
      const float wv[8] = {wlo.x,wlo.y,wlo.z,wlo.w,whi.x,whi.y,whi.z,whi.w};
      #pragma unroll
      for (int j = 0; j < 8; j++) { acc0[j] += x0*wv[j]; acc1[j] += x1*wv[j]; }
    }
  }
  const float4 blo = *(const float4*)(bias + tx*4);
  const float4 bhi = *(const float4*)(bias + 64 + tx*4);
  const float bv[8] = {blo.x,blo.y,blo.z,blo.w,bhi.x,bhi.y,bhi.z,bhi.w};
  #pragma unroll
  for (int j = 0; j < 8; j++) { acc0[j] += bv[j]; acc1[j] += bv[j]; }

  if (OutLds) {
    *(float4*)&OutLds[ty*132 + tx*4]      = make_float4(acc0[0],acc0[1],acc0[2],acc0[3]);
    *(float4*)&OutLds[ty*132 + 64 + tx*4] = make_float4(acc0[4],acc0[5],acc0[6],acc0[7]);
    *(float4*)&OutLds[(16+ty)*132 + tx*4]      = make_float4(acc1[0],acc1[1],acc1[2],acc1[3]);
    *(float4*)&OutLds[(16+ty)*132 + 64 + tx*4] = make_float4(acc1[4],acc1[5],acc1[6],acc1[7]);
  } else {
    ushort4 u;
    u.x = f2bfu(acc0[0]); u.y = f2bfu(acc0[1]); u.z = f2bfu(acc0[2]); u.w = f2bfu(acc0[3]);
    *(ushort4*)(outG + (size_t)ty*128 + tx*4) = u;
    u.x = f2bfu(acc0[4]); u.y = f2bfu(acc0[5]); u.z = f2bfu(acc0[6]); u.w = f2bfu(acc0[7]);
    *(ushort4*)(outG + (size_t)ty*128 + 64 + tx*4) = u;
    if (16 + ty < T_) {
      u.x = f2bfu(acc1[0]); u.y = f2bfu(acc1[1]); u.z = f2bfu(acc1[2]); u.w = f2bfu(acc1[3]);
      *(ushort4*)(outG + (size_t)(16+ty)*128 + tx*4) = u;
      u.x = f2bfu(acc1[4]); u.y = f2bfu(acc1[5]); u.z = f2bfu(acc1[6]); u.w = f2bfu(acc1[7]);
      *(ushort4*)(outG + (size_t)(16+ty)*128 + 64 + tx*4) = u;
    }
  }
}

__global__ __launch_bounds__(256) void k_attn(
    const float* __restrict__ hidden,
    const float* __restrict__ Wq, const float* __restrict__ bq,
    const float* __restrict__ Wk, const float* __restrict__ bk,
    const float* __restrict__ Wv, const float* __restrict__ bv,
    const float* __restrict__ Wo, const float* __restrict__ bo,
    unsigned short* __restrict__ attn)
{
  __shared__ float Xs[32*132];   // X, later ctx (rows 24..31 stay zero)
  __shared__ float Qs[32*132];
  __shared__ float Ks[32*132];
  __shared__ float Vs[32*132];
  __shared__ float Ws[16*128];   // 75.8 KB total -> 2 blocks/CU
  const int tid = threadIdx.x;
  const int bn = (int)blockIdx.x;

  // load X rows 0..23, zero-pad 24..31
  for (int idx = tid; idx < 32*32; idx += 256) {
    const int row = idx >> 5, c4 = (idx & 31) << 2;
    float4 v = make_float4(0.f,0.f,0.f,0.f);
    if (row < T_) v = *(const float4*)(hidden + ((size_t)bn*T_ + row)*D_ + c4);
    *(float4*)&Xs[row*132 + c4] = v;
  }
  __syncthreads();

  proj24(Xs, Ws, Wq, bq, Qs, nullptr, tid);
  proj24(Xs, Ws, Wk, bk, Ks, nullptr, tid);
  proj24(Xs, Ws, Wv, bv, Vs, nullptr, tid);
  __syncthreads();

  // causal softmax(QK^T/4) @ V, one thread per (h,t); ctx -> Xs
  if (tid < H_*T_) {
    const int h = tid / T_, t = tid % T_;
    const int hb = h * 16;
    const float4 q0 = *(const float4*)&Qs[t*132 + hb];
    const float4 q1 = *(const float4*)&Qs[t*132 + hb + 4];
    const float4 q2 = *(const float4*)&Qs[t*132 + hb + 8];
    const float4 q3 = *(const float4*)&Qs[t*132 + hb + 12];
    float p[24];
    float mx = -1e30f;
    #pragma unroll
    for (int s = 0; s < T_; s++) {
      const float4 k0 = *(const float4*)&Ks[s*132 + hb];
      const float4 k1 = *(const float4*)&Ks[s*132 + hb + 4];
      const float4 k2 = *(const float4*)&Ks[s*132 + hb + 8];
      const float4 k3 = *(const float4*)&Ks[s*132 + hb + 12];
      float d;
      d  = q0.x*k0.x; d += q0.y*k0.y; d += q0.z*k0.z; d += q0.w*k0.w;
      d += q1.x*k1.x; d += q1.y*k1.y; d += q1.z*k1.z; d += q1.w*k1.w;
      d += q2.x*k2.x; d += q2.y*k2.y; d += q2.z*k2.z; d += q2.w*k2.w;
      d += q3.x*k3.x; d += q3.y*k3.y; d += q3.z*k3.z; d += q3.w*k3.w;
      d *= 0.25f;                       // scale = 1/sqrt(16)
      d = (s <= t) ? d : -1e30f;        // causal mask
      p[s] = d;
      mx = fmaxf(mx, d);
    }
    float den = 0.f;
    #pragma unroll
    for (int s = 0; s < T_; s++) {
      float e = __expf(p[s] - mx);
      e = (s <= t) ? e : 0.f;
      p[s] = e;
      den += e;
    }
    const float rden = 1.f / den;
    float o[16];
    #pragma unroll
    for (int e = 0; e < 16; e++) o[e] = 0.f;
    #pragma unroll
    for (int s = 0; s < T_; s++) {
      const float ps = p[s];
      const float4 v0 = *(const float4*)&Vs[s*132 + hb];
      const float4 v1 = *(const float4*)&Vs[s*132 + hb + 4];
      const float4 v2 = *(const float4*)&Vs[s*132 + hb + 8];
      const float4 v3 = *(const float4*)&Vs[s*132 + hb + 12];
      o[0]  += ps*v0.x; o[1]  += ps*v0.y; o[2]  += ps*v0.z; o[3]  += ps*v0.w;
      o[4]  += ps*v1.x; o[5]  += ps*v1.y; o[6]  += ps*v1.z; o[7]  += ps*v1.w;
      o[8]  += ps*v2.x; o[9]  += ps*v2.y; o[10] += ps*v2.z; o[11] += ps*v2.w;
      o[12] += ps*v3.x; o[13] += ps*v3.y; o[14] += ps*v3.z; o[15] += ps*v3.w;
    }
    #pragma unroll
    for (int e4 = 0; e4 < 4; e4++) {
      *(float4*)&Xs[t*132 + hb + e4*4] = make_float4(
          o[e4*4+0]*rden, o[e4*4+1]*rden, o[e4*4+2]*rden, o[e4*4+3]*rden);
    }
  }
  __syncthreads();

  proj24(Xs, Ws, Wo, bo, nullptr, attn + (size_t)bn*T_*D_, tid);
}

// ---------------------------------------------------------------------------
// Kernel 3: g = [gcn|attn] @ Wgate^T + bgate  (K=256 in two halves) -> d_out
// ---------------------------------------------------------------------------
__global__ __launch_bounds__(256) void k_gate(
    const unsigned short* __restrict__ gcn, const unsigned short* __restrict__ attn,
    const float* __restrict__ Wgate, const float* __restrict__ bgate,
    float* __restrict__ g)
{
  __shared__ float As[64*20];
  __shared__ float Ws[16*128];
  const int tid = threadIdx.x;
  const int tx = tid & 15, ty = tid >> 4;
  const size_t row0 = (size_t)blockIdx.x * 64;
  const int rA = tid >> 2, cgA = (tid & 3) * 4;
  const int jW = tid & 127, cc0 = (tid >> 7) * 8;

  float acc[4][8];
  #pragma unroll
  for (int i = 0; i < 4; i++)
    #pragma unroll
    for (int j = 0; j < 8; j++) acc[i][j] = 0.f;

  for (int half = 0; half < 2; half++) {
    const unsigned short* src = half ? attn : gcn;
    for (int c0 = 0; c0 < 128; c0 += 16) {
      const ushort4 a4 = *(const ushort4*)(src + (row0 + rA)*D_ + c0 + cgA);
      const float* wrow = Wgate + (size_t)jW*256 + half*128 + c0 + cc0;
      const float4 w0 = *(const float4*)wrow;
      const float4 w1 = *(const float4*)(wrow + 4);
      __syncthreads();
      *(float4*)&As[rA*20 + cgA] =
          make_float4(bfu2f(a4.x), bfu2f(a4.y), bfu2f(a4.z), bfu2f(a4.w));
      Ws[(cc0+0)*128 + jW] = w0.x;
      Ws[(cc0+1)*128 + jW] = w0.y;
      Ws[(cc0+2)*128 + jW] = w0.z;
      Ws[(cc0+3)*128 + jW] = w0.w;
      Ws[(cc0+4)*128 + jW] = w1.x;
      Ws[(cc0+5)*128 + jW] = w1.y;
      Ws[(cc0+6)*128 + jW] = w1.z;
      Ws[(cc0+7)*128 + jW] = w1.w;
      __syncthreads();
      #pragma unroll
      for (int cc = 0; cc < 16; cc++) {
        float a[4];
        #pragma unroll
        for (int i = 0; i < 4; i++) a[i] = As[(ty*4+i)*20 + cc];
        const float4 wlo = *(const float4*)&Ws[cc*128 + tx*4];
        const float4 whi = *(const float4*)&Ws[cc*128 + 64 + tx*4];
        const float wv[8] = {wlo.x,wlo.y,wlo.z,wlo.w,whi.x,whi.y,whi.z,whi.w};
        #pragma unroll
        for (int i = 0; i < 4; i++)
          #pragma unroll
          for (int j = 0; j < 8; j++) acc[i][j] += a[i]*wv[j];
      }
    }
  }

  const float4 blo = *(const float4*)(bgate + tx*4);
  const float4 bhi = *(const float4*)(bgate + 64 + tx*4);
  const float bv[8] = {blo.x,blo.y,blo.z,blo.w,bhi.x,bhi.y,bhi.z,bhi.w};
  #pragma unroll
  for (int i = 0; i < 4; i++) {
    float* grow = g + (row0 + (size_t)(ty*4+i))*D_;
    *(float4*)&grow[tx*4] = make_float4(acc[i][0]+bv[0], acc[i][1]+bv[1],
                                        acc[i][2]+bv[2], acc[i][3]+bv[3]);
    *(float4*)&grow[64 + tx*4] = make_float4(acc[i][4]+bv[4], acc[i][5]+bv[5],
                                             acc[i][6]+bv[6], acc[i][7]+bv[7]);
  }
}

// ---------------------------------------------------------------------------
// Kernels 4/5: deterministic two-stage batch-norm statistics over (B,N,T)
// ---------------------------------------------------------------------------
__global__ __launch_bounds__(256) void k_bnstats(
    const float* __restrict__ g, float* __restrict__ psum, float* __restrict__ psq)
{
  const int tid = threadIdx.x;
  const int ch = tid & 127, sub = tid >> 7;
  const size_t r0 = (size_t)blockIdx.x * 311;
  size_t r1 = r0 + 311; if (r1 > (size_t)MROWS) r1 = (size_t)MROWS;
  float s = 0.f, q = 0.f;
  for (size_t r = r0 + sub; r < r1; r += 2) {
    const float x = g[r*D_ + ch];
    s += x; q += x*x;
  }
  __shared__ float ls[256], lq[256];
  ls[tid] = s; lq[tid] = q;
  __syncthreads();
  if (tid < 128) {
    psum[(size_t)blockIdx.x*128 + tid] = ls[tid] + ls[tid+128];
    psq [(size_t)blockIdx.x*128 + tid] = lq[tid] + lq[tid+128];
  }
}

__global__ __launch_bounds__(128) void k_bnfinal(
    const float* __restrict__ psum, const float* __restrict__ psq,
    float* __restrict__ meanv, float* __restrict__ invstdv)
{
  const int ch = threadIdx.x;
  float s = 0.f, q = 0.f;
  for (int i = 0; i < NBLK_BN; i++) { s += psum[(size_t)i*128 + ch]; q += psq[(size_t)i*128 + ch]; }
  const float mean = s / (float)MROWS;
  const float var  = q / (float)MROWS - mean*mean;
  meanv[ch] = mean;
  invstdv[ch] = rsqrtf(var + EPS_);
}

// ---------------------------------------------------------------------------
// Kernel 6: z = sigmoid(BN(g)); out = z*gcn + (1-z)*attn   (in-place on d_out)
// ---------------------------------------------------------------------------
__global__ __launch_bounds__(256) void k_final(
    float* __restrict__ g,
    const unsigned short* __restrict__ gcn, const unsigned short* __restrict__ attn,
    const float* __restrict__ meanv, const float* __restrict__ invstdv,
    const float* __restrict__ gamma, const float* __restrict__ beta)
{
  const size_t tot4 = SELEMS >> 2;
  for (size_t i4 = (size_t)blockIdx.x*blockDim.x + threadIdx.x; i4 < tot4;
       i4 += (size_t)gridDim.x*blockDim.x) {
    const int c4 = (int)(i4 & 31) * 4;
    const float4 gv = ((const float4*)g)[i4];
    const ushort4 gc = ((const ushort4*)gcn)[i4];
    const ushort4 at = ((const ushort4*)attn)[i4];
    const float4 m4 = *(const float4*)(meanv + c4);
    const float4 s4 = *(const float4*)(invstdv + c4);
    const float4 ga = *(const float4*)(gamma + c4);
    const float4 be = *(const float4*)(beta + c4);
    float4 outv;
    { const float y = (gv.x - m4.x)*s4.x*ga.x + be.x;
      const float z = 1.f/(1.f + __expf(-y));
      outv.x = z*bfu2f(gc.x) + (1.f - z)*bfu2f(at.x); }
    { const float y = (gv.y - m4.y)*s4.y*ga.y + be.y;
      const float z = 1.f/(1.f + __expf(-y));
      outv.y = z*bfu2f(gc.y) + (1.f - z)*bfu2f(at.y); }
    { const float y = (gv.z - m4.z)*s4.z*ga.z + be.z;
      const float z = 1.f/(1.f + __expf(-y));
      outv.z = z*bfu2f(gc.z) + (1.f - z)*bfu2f(at.z); }
    { const float y = (gv.w - m4.w)*s4.w*ga.w + be.w;
      const float z = 1.f/(1.f + __expf(-y));
      outv.w = z*bfu2f(gc.w) + (1.f - z)*bfu2f(at.w); }
    ((float4*)g)[i4] = outv;
  }
}

// ---------------------------------------------------------------------------
extern "C" void kernel_launch(void* const* d_in, const int* in_sizes, int n_in,
                              void* d_out, int out_size, void* d_ws, size_t ws_size,
                              hipStream_t stream)
{
  (void)in_sizes; (void)n_in; (void)out_size; (void)ws_size;
  const float* hidden = (const float*)d_in[0];
  const float* matrix = (const float*)d_in[1];
  const float* Wq   = (const float*)d_in[2];  const float* bq    = (const float*)d_in[3];
  const float* Wk   = (const float*)d_in[4];  const float* bk    = (const float*)d_in[5];
  const float* Wv   = (const float*)d_in[6];  const float* bv    = (const float*)d_in[7];
  const float* Wo   = (const float*)d_in[8];  const float* bo    = (const float*)d_in[9];
  const float* Wgcn = (const float*)d_in[10]; const float* bgcn  = (const float*)d_in[11];
  const float* Wgate= (const float*)d_in[12]; const float* bgate = (const float*)d_in[13];
  const float* gamma= (const float*)d_in[14]; const float* beta  = (const float*)d_in[15];
  float* out = (float*)d_out;

  unsigned short* gcn  = (unsigned short*)d_ws;
  unsigned short* attn = gcn + SELEMS;
  float* psum    = (float*)(attn + SELEMS);
  float* psq     = psum + (size_t)NBLK_BN*128;
  float* meanv   = psq  + (size_t)NBLK_BN*128;
  float* invstdv = meanv + 128;

  k_gcn  <<<dim3(4, B_*T_), 256, 0, stream>>>(hidden, matrix, Wgcn, bgcn, gcn);
  k_attn <<<B_*N_,          256, 0, stream>>>(hidden, Wq,bq, Wk,bk, Wv,bv, Wo,bo, attn);
  k_gate <<<MROWS/64,       256, 0, stream>>>(gcn, attn, Wgate, bgate, out);
  k_bnstats<<<NBLK_BN,      256, 0, stream>>>(out, psum, psq);
  k_bnfinal<<<1,            128, 0, stream>>>(psum, psq, meanv, invstdv);
  k_final<<<2048,           256, 0, stream>>>(out, gcn, attn, meanv, invstdv, gamma, beta);
}

// Round 4
// 1162.239 us; speedup vs baseline: 1.7668x; 1.7668x over previous
//
#include <hip/hip_runtime.h>

#define B_ 64
#define N_ 207
#define T_ 24
#define D_ 128
#define H_ 8
#define MROWS (B_*N_*T_)             // 317952 = 128*2484
#define SELEMS ((size_t)MROWS * D_)  // 40697856
#define NBLK_BN 256
#define BN_ROWS 1242                 // 256*1242 = 317952 exactly
#define EPS_ 1e-5f

typedef __attribute__((ext_vector_type(8))) short s16x8;   // 8 bf16 (4 VGPR)
typedef __attribute__((ext_vector_type(4))) float f32x4;   // MFMA acc

#define MFMA16(a,b,c) __builtin_amdgcn_mfma_f32_16x16x32_bf16(a,b,c,0,0,0)

__device__ __forceinline__ float bfu2f(unsigned short u) {
  return __uint_as_float(((unsigned int)u) << 16);
}
__device__ __forceinline__ unsigned short f2bfu(float f) {
  unsigned int x = __float_as_uint(f);
  return (unsigned short)((x + 0x7fffu + ((x >> 16) & 1u)) >> 16);  // RNE
}

__device__ __forceinline__ s16x8 fragA_from_f32(const float* __restrict__ p) {
  const float4 a = *(const float4*)p;
  const float4 b = *(const float4*)(p + 4);
  s16x8 r;
  r[0] = (short)f2bfu(a.x); r[1] = (short)f2bfu(a.y);
  r[2] = (short)f2bfu(a.z); r[3] = (short)f2bfu(a.w);
  r[4] = (short)f2bfu(b.x); r[5] = (short)f2bfu(b.y);
  r[6] = (short)f2bfu(b.z); r[7] = (short)f2bfu(b.w);
  return r;
}

// Epilogue: acc[2 Mtiles][8 Ntiles] (+bias) -> bf16, repacked per-wave through
// LDS (32x128 tile, stride 136 ushorts) -> coalesced 16B stores.
// C/D layout: col = lane&15, row = (lane>>4)*4 + reg  [m89/m91 verified].
// Read-back: 512 groups of 8 cols; 16 groups/row -> row = c>>4, colbase=(c&15)*8.
__device__ __forceinline__ void epi_store_bf16(
    const f32x4 acc[2][8], const float* __restrict__ bias,
    unsigned short* __restrict__ Obase, unsigned short* __restrict__ lb, int l)
{
  const int lr = l & 15, lg = l >> 4;
  #pragma unroll
  for (int nt = 0; nt < 8; nt++) {
    const float b = bias[nt*16 + lr];
    #pragma unroll
    for (int mt = 0; mt < 2; mt++)
      #pragma unroll
      for (int r = 0; r < 4; r++)
        lb[(mt*16 + lg*4 + r)*136 + nt*16 + lr] = f2bfu(acc[mt][nt][r] + b);
  }
  // wave-local write->read on same LDS pointer: compiler inserts lgkmcnt waits
  #pragma unroll
  for (int p = 0; p < 8; p++) {
    const int c = p*64 + l;                 // 0..511
    const int row = c >> 4, c8 = (c & 15) * 8;   // 32 rows x 16 groups  [R3 fix]
    const s16x8 v = *(const s16x8*)&lb[row*136 + c8];
    *(s16x8*)(Obase + (size_t)row*D_ + c8) = v;
  }
}

// ---------------------------------------------------------------------------
// Weight cast: Wq|Wk|Wv|Wo|Wgcn (128x128 each) | Wgate (128x256) -> bf16
// ---------------------------------------------------------------------------
__global__ __launch_bounds__(256) void k_wcast(
    const float* __restrict__ Wq, const float* __restrict__ Wk,
    const float* __restrict__ Wv, const float* __restrict__ Wo,
    const float* __restrict__ Wgcn, const float* __restrict__ Wgate,
    unsigned short* __restrict__ out)
{
  const int idx4 = (blockIdx.x * 256 + threadIdx.x) * 4;
  if (idx4 >= 114688) return;
  const float* src; int off;
  if      (idx4 < 16384) { src = Wq;    off = idx4; }
  else if (idx4 < 32768) { src = Wk;    off = idx4 - 16384; }
  else if (idx4 < 49152) { src = Wv;    off = idx4 - 32768; }
  else if (idx4 < 65536) { src = Wo;    off = idx4 - 49152; }
  else if (idx4 < 81920) { src = Wgcn;  off = idx4 - 65536; }
  else                   { src = Wgate; off = idx4 - 81920; }
  const float4 v = *(const float4*)(src + off);
  ushort4 u;
  u.x = f2bfu(v.x); u.y = f2bfu(v.y); u.z = f2bfu(v.z); u.w = f2bfu(v.w);
  *(ushort4*)(out + idx4) = u;
}

// ---------------------------------------------------------------------------
// QKV: [MROWS,128] fp32 hidden -> Q,K,V bf16 via 3 fused MFMA GEMMs.
// Block 256 thr = 4 waves; BM=128 (wave w owns rows m0+32w..+31, 2 M-tiles).
// ---------------------------------------------------------------------------
__global__ __launch_bounds__(256) void k_qkv(
    const float* __restrict__ hidden,
    const unsigned short* __restrict__ Wqb, const unsigned short* __restrict__ Wkb,
    const unsigned short* __restrict__ Wvb,
    const float* __restrict__ bq, const float* __restrict__ bk,
    const float* __restrict__ bv,
    unsigned short* __restrict__ Q, unsigned short* __restrict__ K,
    unsigned short* __restrict__ V)
{
  __shared__ __align__(16) unsigned short lbuf[4][32*136];
  const int tid = threadIdx.x;
  const int w = tid >> 6, l = tid & 63;
  const int lr = l & 15, lg = l >> 4;
  const size_t m0 = (size_t)blockIdx.x * 128 + w * 32;

  s16x8 afr[2][4];
  #pragma unroll
  for (int mt = 0; mt < 2; mt++)
    #pragma unroll
    for (int ks = 0; ks < 4; ks++)
      afr[mt][ks] = fragA_from_f32(hidden + (m0 + mt*16 + lr)*D_ + ks*32 + lg*8);

  const unsigned short* Ws[3] = {Wqb, Wkb, Wvb};
  const float*          bs[3] = {bq, bk, bv};
  unsigned short*       Os[3] = {Q, K, V};
  #pragma unroll
  for (int out = 0; out < 3; out++) {
    const unsigned short* W = Ws[out];
    f32x4 acc[2][8];
    #pragma unroll
    for (int mt = 0; mt < 2; mt++)
      #pragma unroll
      for (int nt = 0; nt < 8; nt++)
        #pragma unroll
        for (int e = 0; e < 4; e++) acc[mt][nt][e] = 0.f;
    #pragma unroll
    for (int ks = 0; ks < 4; ks++) {
      #pragma unroll
      for (int nt = 0; nt < 8; nt++) {
        const s16x8 bf = *(const s16x8*)(W + (size_t)(nt*16 + lr)*D_ + ks*32 + lg*8);
        acc[0][nt] = MFMA16(afr[0][ks], bf, acc[0][nt]);
        acc[1][nt] = MFMA16(afr[1][ks], bf, acc[1][nt]);
      }
    }
    epi_store_bf16(acc, bs[out], Os[out] + m0*D_, lbuf[w], l);
  }
}

// ---------------------------------------------------------------------------
// Generic projection GEMM: Out[M,128] = A[M,KSRC*128] @ Wb^T + bias.
// KSRC=2: A = concat(A0,A1) along K. OUTF32: fp32 direct store (gate -> d_out).
// ---------------------------------------------------------------------------
template<int KSRC, bool OUTF32>
__global__ __launch_bounds__(256) void k_proj(
    const unsigned short* __restrict__ A0, const unsigned short* __restrict__ A1,
    const unsigned short* __restrict__ Wb, const float* __restrict__ bias,
    void* __restrict__ OutP)
{
  __shared__ __align__(16) unsigned short lbuf[4][32*136];
  const int tid = threadIdx.x;
  const int w = tid >> 6, l = tid & 63;
  const int lr = l & 15, lg = l >> 4;
  const size_t m0 = (size_t)blockIdx.x * 128 + w * 32;
  const int KW = KSRC * 128;

  f32x4 acc[2][8];
  #pragma unroll
  for (int mt = 0; mt < 2; mt++)
    #pragma unroll
    for (int nt = 0; nt < 8; nt++)
      #pragma unroll
      for (int e = 0; e < 4; e++) acc[mt][nt][e] = 0.f;

  #pragma unroll
  for (int ks = 0; ks < KSRC*4; ks++) {
    const unsigned short* Asrc = (KSRC == 2 && ks >= 4) ? A1 : A0;
    const int kk = (KSRC == 2 && ks >= 4) ? ks - 4 : ks;
    const s16x8 a0 = *(const s16x8*)(Asrc + (m0 +  0 + lr)*D_ + kk*32 + lg*8);
    const s16x8 a1 = *(const s16x8*)(Asrc + (m0 + 16 + lr)*D_ + kk*32 + lg*8);
    #pragma unroll
    for (int nt = 0; nt < 8; nt++) {
      const s16x8 bf = *(const s16x8*)(Wb + (size_t)(nt*16 + lr)*KW + ks*32 + lg*8);
      acc[0][nt] = MFMA16(a0, bf, acc[0][nt]);
      acc[1][nt] = MFMA16(a1, bf, acc[1][nt]);
    }
  }

  if (OUTF32) {
    float* Out = (float*)OutP;
    #pragma unroll
    for (int nt = 0; nt < 8; nt++) {
      const float b = bias[nt*16 + lr];
      #pragma unroll
      for (int mt = 0; mt < 2; mt++)
        #pragma unroll
        for (int r = 0; r < 4; r++)
          Out[(m0 + mt*16 + lg*4 + r)*D_ + nt*16 + lr] = acc[mt][nt][r] + b;
    }
  } else {
    epi_store_bf16(acc, bias, (unsigned short*)OutP + m0*D_, lbuf[w], l);
  }
}

// ---------------------------------------------------------------------------
// Attention core: per (b,n), causal softmax(QK^T/4)@V on VALU. 192 thr=(h,t).
// ctx written in-place over Q (block-local rows; Q consumed via LDS first).
// ---------------------------------------------------------------------------
__global__ __launch_bounds__(192) void k_attn2(
    const unsigned short* __restrict__ Q, const unsigned short* __restrict__ K,
    const unsigned short* __restrict__ V, unsigned short* __restrict__ CTX)
{
  __shared__ __align__(16) unsigned short Qs[T_*D_], Ks[T_*D_], Vs[T_*D_];
  const int tid = threadIdx.x;
  const size_t base = (size_t)blockIdx.x * (T_*D_);
  for (int i = tid; i < (T_*D_)/8; i += 192) {
    ((int4*)Qs)[i] = ((const int4*)(Q + base))[i];
    ((int4*)Ks)[i] = ((const int4*)(K + base))[i];
    ((int4*)Vs)[i] = ((const int4*)(V + base))[i];
  }
  __syncthreads();

  const int h = tid / T_, t = tid % T_;
  const int hb = h * 16;
  float q[16];
  #pragma unroll
  for (int e = 0; e < 16; e++) q[e] = bfu2f(Qs[t*D_ + hb + e]);

  float p[T_];
  float mx = -1e30f;
  #pragma unroll
  for (int s = 0; s < T_; s++) {
    float d = 0.f;
    #pragma unroll
    for (int e = 0; e < 16; e++) d += q[e] * bfu2f(Ks[s*D_ + hb + e]);
    d *= 0.25f;                      // 1/sqrt(DK=16)
    d = (s <= t) ? d : -1e30f;
    p[s] = d;
    mx = fmaxf(mx, d);
  }
  float den = 0.f;
  #pragma unroll
  for (int s = 0; s < T_; s++) {
    float e = __expf(p[s] - mx);
    e = (s <= t) ? e : 0.f;
    p[s] = e;
    den += e;
  }
  const float rd = 1.f / den;
  float o[16];
  #pragma unroll
  for (int e = 0; e < 16; e++) o[e] = 0.f;
  #pragma unroll
  for (int s = 0; s < T_; s++) {
    const float ps = p[s];
    #pragma unroll
    for (int e = 0; e < 16; e++) o[e] += ps * bfu2f(Vs[s*D_ + hb + e]);
  }
  s16x8 r0, r1;
  #pragma unroll
  for (int e = 0; e < 8; e++) { r0[e] = (short)f2bfu(o[e]*rd); r1[e] = (short)f2bfu(o[8+e]*rd); }
  *(s16x8*)(CTX + base + (size_t)t*D_ + hb)     = r0;
  *(s16x8*)(CTX + base + (size_t)t*D_ + hb + 8) = r1;
}

// ---------------------------------------------------------------------------
// GCN aggregation (fp32 VALU): agg[b,m,t,:] = sum_n matrix[b,t,n,m]*hidden[b,n,t,:]
// ---------------------------------------------------------------------------
__global__ __launch_bounds__(256) void k_agg(
    const float* __restrict__ hidden, const float* __restrict__ matrix,
    unsigned short* __restrict__ agg)
{
  __shared__ float smem[3136];   // Ms[16][64] + Hs[16][132]
  float* Ms = smem;
  float* Hs = smem + 1024;

  const int tid = threadIdx.x;
  const int tx = tid & 15, ty = tid >> 4;
  const int m0 = blockIdx.x * 64;
  const int bt = (int)blockIdx.y;
  const int b = bt / T_, t = bt % T_;

  float acc[4][8];
  #pragma unroll
  for (int i = 0; i < 4; i++)
    #pragma unroll
    for (int j = 0; j < 8; j++) acc[i][j] = 0.f;

  const int kk = ty;
  const int hc = tx * 8;

  for (int n0 = 0; n0 < N_; n0 += 16) {
    const int n = n0 + kk;
    const bool nok = (n < N_);
    const int nsafe = nok ? n : 0;
    float mv[4];
    const float* mrow = matrix + ((size_t)(b*T_ + t)*N_ + nsafe)*N_ + m0;
    #pragma unroll
    for (int i = 0; i < 4; i++) {
      const int mm = tx + 16*i;
      mv[i] = (nok && (m0 + mm) < N_) ? mrow[mm] : 0.f;
    }
    float4 h0 = make_float4(0.f,0.f,0.f,0.f), h1 = make_float4(0.f,0.f,0.f,0.f);
    if (nok) {
      const float* hrow = hidden + (((size_t)b*N_ + n)*T_ + t)*D_ + hc;
      h0 = *(const float4*)(hrow);
      h1 = *(const float4*)(hrow + 4);
    }
    __syncthreads();
    #pragma unroll
    for (int i = 0; i < 4; i++) Ms[kk*64 + tx + 16*i] = mv[i];
    *(float4*)&Hs[kk*132 + hc]     = h0;
    *(float4*)&Hs[kk*132 + hc + 4] = h1;
    __syncthreads();
    #pragma unroll
    for (int k2 = 0; k2 < 16; k2++) {
      float a[4];
      #pragma unroll
      for (int i = 0; i < 4; i++) a[i] = Ms[k2*64 + ty*4 + i];
      const float4 hlo = *(const float4*)&Hs[k2*132 + tx*4];
      const float4 hhi = *(const float4*)&Hs[k2*132 + 64 + tx*4];
      const float hv[8] = {hlo.x,hlo.y,hlo.z,hlo.w,hhi.x,hhi.y,hhi.z,hhi.w};
      #pragma unroll
      for (int i = 0; i < 4; i++)
        #pragma unroll
        for (int j = 0; j < 8; j++) acc[i][j] += a[i]*hv[j];
    }
  }

  #pragma unroll
  for (int i = 0; i < 4; i++) {
    const int m = m0 + ty*4 + i;
    if (m < N_) {
      unsigned short* orow = agg + (((size_t)b*N_ + m)*T_ + t)*D_;
      ushort4 ulo, uhi;
      ulo.x = f2bfu(acc[i][0]); ulo.y = f2bfu(acc[i][1]);
      ulo.z = f2bfu(acc[i][2]); ulo.w = f2bfu(acc[i][3]);
      uhi.x = f2bfu(acc[i][4]); uhi.y = f2bfu(acc[i][5]);
      uhi.z = f2bfu(acc[i][6]); uhi.w = f2bfu(acc[i][7]);
      *(ushort4*)(orow + tx*4)      = ulo;
      *(ushort4*)(orow + 64 + tx*4) = uhi;
    }
  }
}

// ---------------------------------------------------------------------------
// BN statistics (deterministic two-stage) + final blend
// ---------------------------------------------------------------------------
__global__ __launch_bounds__(256) void k_bnstats(
    const float* __restrict__ g, float* __restrict__ psum, float* __restrict__ psq)
{
  const int tid = threadIdx.x;
  const int ch = tid & 127, sub = tid >> 7;
  const size_t r0 = (size_t)blockIdx.x * BN_ROWS;
  size_t r1 = r0 + BN_ROWS; if (r1 > (size_t)MROWS) r1 = (size_t)MROWS;
  float s = 0.f, q = 0.f;
  for (size_t r = r0 + sub; r < r1; r += 2) {
    const float x = g[r*D_ + ch];
    s += x; q += x*x;
  }
  __shared__ float ls[256], lq[256];
  ls[tid] = s; lq[tid] = q;
  __syncthreads();
  if (tid < 128) {
    psum[(size_t)blockIdx.x*128 + tid] = ls[tid] + ls[tid+128];
    psq [(size_t)blockIdx.x*128 + tid] = lq[tid] + lq[tid+128];
  }
}

__global__ __launch_bounds__(128) void k_bnfinal(
    const float* __restrict__ psum, const float* __restrict__ psq,
    float* __restrict__ meanv, float* __restrict__ invstdv)
{
  const int ch = threadIdx.x;
  float s = 0.f, q = 0.f;
  for (int i = 0; i < NBLK_BN; i++) { s += psum[(size_t)i*128 + ch]; q += psq[(size_t)i*128 + ch]; }
  const float mean = s / (float)MROWS;
  const float var  = q / (float)MROWS - mean*mean;
  meanv[ch] = mean;
  invstdv[ch] = rsqrtf(var + EPS_);
}

__global__ __launch_bounds__(256) void k_final(
    float* __restrict__ g,
    const unsigned short* __restrict__ gcn, const unsigned short* __restrict__ attn,
    const float* __restrict__ meanv, const float* __restrict__ invstdv,
    const float* __restrict__ gamma, const float* __restrict__ beta)
{
  const size_t tot4 = SELEMS >> 2;
  for (size_t i4 = (size_t)blockIdx.x*blockDim.x + threadIdx.x; i4 < tot4;
       i4 += (size_t)gridDim.x*blockDim.x) {
    const int c4 = (int)(i4 & 31) * 4;
    const float4 gv = ((const float4*)g)[i4];
    const ushort4 gc = ((const ushort4*)gcn)[i4];
    const ushort4 at = ((const ushort4*)attn)[i4];
    const float4 m4 = *(const float4*)(meanv + c4);
    const float4 s4 = *(const float4*)(invstdv + c4);
    const float4 ga = *(const float4*)(gamma + c4);
    const float4 be = *(const float4*)(beta + c4);
    float4 outv;
    { const float y = (gv.x - m4.x)*s4.x*ga.x + be.x;
      const float z = 1.f/(1.f + __expf(-y));
      outv.x = z*bfu2f(gc.x) + (1.f - z)*bfu2f(at.x); }
    { const float y = (gv.y - m4.y)*s4.y*ga.y + be.y;
      const float z = 1.f/(1.f + __expf(-y));
      outv.y = z*bfu2f(gc.y) + (1.f - z)*bfu2f(at.y); }
    { const float y = (gv.z - m4.z)*s4.z*ga.z + be.z;
      const float z = 1.f/(1.f + __expf(-y));
      outv.z = z*bfu2f(gc.z) + (1.f - z)*bfu2f(at.z); }
    { const float y = (gv.w - m4.w)*s4.w*ga.w + be.w;
      const float z = 1.f/(1.f + __expf(-y));
      outv.w = z*bfu2f(gc.w) + (1.f - z)*bfu2f(at.w); }
    ((float4*)g)[i4] = outv;
  }
}

// ---------------------------------------------------------------------------
extern "C" void kernel_launch(void* const* d_in, const int* in_sizes, int n_in,
                              void* d_out, int out_size, void* d_ws, size_t ws_size,
                              hipStream_t stream)
{
  (void)in_sizes; (void)n_in; (void)out_size; (void)ws_size;
  const float* hidden = (const float*)d_in[0];
  const float* matrix = (const float*)d_in[1];
  const float* Wq   = (const float*)d_in[2];  const float* bq    = (const float*)d_in[3];
  const float* Wk   = (const float*)d_in[4];  const float* bk    = (const float*)d_in[5];
  const float* Wv   = (const float*)d_in[6];  const float* bv    = (const float*)d_in[7];
  const float* Wo   = (const float*)d_in[8];  const float* bo    = (const float*)d_in[9];
  const float* Wgcn = (const float*)d_in[10]; const float* bgcn  = (const float*)d_in[11];
  const float* Wgate= (const float*)d_in[12]; const float* bgate = (const float*)d_in[13];
  const float* gamma= (const float*)d_in[14]; const float* beta  = (const float*)d_in[15];
  float* out = (float*)d_out;

  // ws (155.7 MiB): weights bf16 | X1 bf16[SELEMS] | X2 bf16[SELEMS] | stats
  unsigned short* WB = (unsigned short*)d_ws;
  unsigned short* Wqb    = WB;
  unsigned short* Wkb    = WB + 16384;
  unsigned short* Wvb    = WB + 32768;
  unsigned short* Wob    = WB + 49152;
  unsigned short* Wgcnb  = WB + 65536;
  unsigned short* Wgateb = WB + 81920;          // 32768 elems
  unsigned short* X1     = WB + 114688;
  unsigned short* X2     = X1 + SELEMS;
  float* psum    = (float*)(X2 + SELEMS);
  float* psq     = psum + (size_t)NBLK_BN*128;
  float* meanv   = psq  + (size_t)NBLK_BN*128;
  float* invstdv = meanv + 128;

  // d_out as bf16 scratch until the gate GEMM: D1 = lo half, D2 = hi half
  unsigned short* D1 = (unsigned short*)d_out;
  unsigned short* D2 = D1 + SELEMS;

  k_wcast<<<112, 256, 0, stream>>>(Wq, Wk, Wv, Wo, Wgcn, Wgate, WB);
  k_agg  <<<dim3(4, B_*T_), 256, 0, stream>>>(hidden, matrix, X1);       // agg -> X1
  k_proj<1,false><<<MROWS/128, 256, 0, stream>>>(X1, nullptr, Wgcnb, bgcn, X2);  // gcn -> X2
  k_qkv  <<<MROWS/128, 256, 0, stream>>>(hidden, Wqb, Wkb, Wvb, bq, bk, bv,
                                         D1, D2, X1);                    // Q,K,V (agg dead)
  k_attn2<<<B_*N_, 192, 0, stream>>>(D1, D2, X1, D1);                    // ctx over Q
  k_proj<1,false><<<MROWS/128, 256, 0, stream>>>(D1, nullptr, Wob, bo, X1);      // attn -> X1 (V dead)
  k_proj<2,true ><<<MROWS/128, 256, 0, stream>>>(X2, X1, Wgateb, bgate, (void*)out); // g -> d_out
  k_bnstats<<<NBLK_BN, 256, 0, stream>>>(out, psum, psq);
  k_bnfinal<<<1, 128, 0, stream>>>(psum, psq, meanv, invstdv);
  k_final<<<2048, 256, 0, stream>>>(out, X2, X1, meanv, invstdv, gamma, beta);
}

// Round 5
// 975.225 us; speedup vs baseline: 2.1056x; 1.1918x over previous
//
#include <hip/hip_runtime.h>

#define B_ 64
#define N_ 207
#define T_ 24
#define D_ 128
#define H_ 8
#define MROWS (B_*N_*T_)             // 317952 = 128*2484
#define SELEMS ((size_t)MROWS * D_)  // 40697856
#define NBLK_BN 256
#define BN_ROWS 1242                 // 256*1242 = 317952 exactly
#define EPS_ 1e-5f

typedef __attribute__((ext_vector_type(8))) short s16x8;   // 8 bf16 (4 VGPR)
typedef __attribute__((ext_vector_type(4))) float f32x4;   // MFMA acc

#define MFMA16(a,b,c) __builtin_amdgcn_mfma_f32_16x16x32_bf16(a,b,c,0,0,0)

__device__ __forceinline__ float bfu2f(unsigned short u) {
  return __uint_as_float(((unsigned int)u) << 16);
}
__device__ __forceinline__ unsigned short f2bfu(float f) {
  unsigned int x = __float_as_uint(f);
  return (unsigned short)((x + 0x7fffu + ((x >> 16) & 1u)) >> 16);  // RNE
}
__device__ __forceinline__ unsigned int packbf2(float lo, float hi) {
  return (unsigned int)f2bfu(lo) | ((unsigned int)f2bfu(hi) << 16);
}

__device__ __forceinline__ s16x8 fragA_from_f32(const float* __restrict__ p) {
  const float4 a = *(const float4*)p;
  const float4 b = *(const float4*)(p + 4);
  s16x8 r;
  r[0] = (short)f2bfu(a.x); r[1] = (short)f2bfu(a.y);
  r[2] = (short)f2bfu(a.z); r[3] = (short)f2bfu(a.w);
  r[4] = (short)f2bfu(b.x); r[5] = (short)f2bfu(b.y);
  r[6] = (short)f2bfu(b.z); r[7] = (short)f2bfu(b.w);
  return r;
}

// Epilogue: acc[2 Mtiles][8 Ntiles] (+bias) -> bf16, repacked per-wave through
// LDS (32x128 tile, stride 136 ushorts) -> coalesced 16B stores.
// C/D layout: col = lane&15, row = (lane>>4)*4 + reg  [m89/m91 verified].
__device__ __forceinline__ void epi_store_bf16(
    const f32x4 acc[2][8], const float* __restrict__ bias,
    unsigned short* __restrict__ Obase, unsigned short* __restrict__ lb, int l)
{
  const int lr = l & 15, lg = l >> 4;
  #pragma unroll
  for (int nt = 0; nt < 8; nt++) {
    const float b = bias[nt*16 + lr];
    #pragma unroll
    for (int mt = 0; mt < 2; mt++)
      #pragma unroll
      for (int r = 0; r < 4; r++)
        lb[(mt*16 + lg*4 + r)*136 + nt*16 + lr] = f2bfu(acc[mt][nt][r] + b);
  }
  #pragma unroll
  for (int p = 0; p < 8; p++) {
    const int c = p*64 + l;                      // 0..511
    const int row = c >> 4, c8 = (c & 15) * 8;   // 32 rows x 16 groups
    const s16x8 v = *(const s16x8*)&lb[row*136 + c8];
    *(s16x8*)(Obase + (size_t)row*D_ + c8) = v;
  }
}

// ---------------------------------------------------------------------------
// Weight cast: Wq|Wk|Wv|Wo|Wgcn (128x128 each) | Wgate (128x256) -> bf16
// ---------------------------------------------------------------------------
__global__ __launch_bounds__(256) void k_wcast(
    const float* __restrict__ Wq, const float* __restrict__ Wk,
    const float* __restrict__ Wv, const float* __restrict__ Wo,
    const float* __restrict__ Wgcn, const float* __restrict__ Wgate,
    unsigned short* __restrict__ out)
{
  const int idx4 = (blockIdx.x * 256 + threadIdx.x) * 4;
  if (idx4 >= 114688) return;
  const float* src; int off;
  if      (idx4 < 16384) { src = Wq;    off = idx4; }
  else if (idx4 < 32768) { src = Wk;    off = idx4 - 16384; }
  else if (idx4 < 49152) { src = Wv;    off = idx4 - 32768; }
  else if (idx4 < 65536) { src = Wo;    off = idx4 - 49152; }
  else if (idx4 < 81920) { src = Wgcn;  off = idx4 - 65536; }
  else                   { src = Wgate; off = idx4 - 81920; }
  const float4 v = *(const float4*)(src + off);
  ushort4 u;
  u.x = f2bfu(v.x); u.y = f2bfu(v.y); u.z = f2bfu(v.z); u.w = f2bfu(v.w);
  *(ushort4*)(out + idx4) = u;
}

// ---------------------------------------------------------------------------
// Fused GCN branch (MFMA): per (b,t):
//   phase1: agg[m,c] = sum_n matrix[b,t,n,m] * hidden[b,n,t,c]   (K=207)
//   phase2: gcn[m,:] = agg[m,:] @ Wgcn^T + bgcn                  (K=128)
// Block: 256 thr = 4 waves; tile 128(m) x 128(c); grid (2, B*T).
// Both phase-1 operands are K-major in memory -> staged transposed into LDS
// as bf16 pair-packed u32 (row stride 40 u16 = 80 B, 16B-aligned b128 reads).
// ---------------------------------------------------------------------------
__global__ __launch_bounds__(256) void k_gcn2(
    const float* __restrict__ hidden, const float* __restrict__ matrix,
    const unsigned short* __restrict__ Wgcnb, const float* __restrict__ bgcn,
    unsigned short* __restrict__ gcn)
{
  __shared__ __align__(16) unsigned char smem[34816];
  unsigned short* Ms16 = (unsigned short*)smem;            // [128 m][40 k]
  unsigned int*   Ms32 = (unsigned int*)smem;
  unsigned short* Hs16 = (unsigned short*)(smem + 10240);  // [128 c][40 k]
  unsigned int*   Hs32 = (unsigned int*)(smem + 10240);
  unsigned short* GsAll = (unsigned short*)smem;           // phase2: [4][32*136]

  const int tid = threadIdx.x;
  const int w = tid >> 6, l = tid & 63;
  const int lr = l & 15, lg = l >> 4;
  const int m0 = blockIdx.x * 128;
  const int by = (int)blockIdx.y;
  const int b = by / T_, t = by % T_;

  const int nn = (tid & 15) * 2;      // chunk-local row pair
  const int cb = (tid >> 4) * 8;      // 8-wide m (or c) group, 0..120

  const float* mbase = matrix + (size_t)(b*T_ + t)*N_*N_;           // + n*N_ + m
  const float* hbase = hidden + (size_t)b*N_*T_*D_ + (size_t)t*D_;  // + n*T_*D_ + c

  f32x4 acc1[2][8];
  #pragma unroll
  for (int mt = 0; mt < 2; mt++)
    #pragma unroll
    for (int nt = 0; nt < 8; nt++)
      #pragma unroll
      for (int e = 0; e < 4; e++) acc1[mt][nt][e] = 0.f;

  for (int ch = 0; ch < 7; ++ch) {
    const int n0 = ch * 32;
    const int n_r0 = n0 + nn, n_r1 = n_r0 + 1;
    const bool rv0 = (n_r0 < N_), rv1 = (n_r1 < N_);
    const size_t nc0 = (size_t)(rv0 ? n_r0 : 0);
    const size_t nc1 = (size_t)(rv1 ? n_r1 : 0);

    // ---- matrix tile [32 n][128 m] -> regs (masked)
    float va[8], vb[8];
    {
      const float* r0 = mbase + nc0*N_ + m0 + cb;
      const float* r1 = mbase + nc1*N_ + m0 + cb;
      #pragma unroll
      for (int j = 0; j < 2; ++j) {
        const int mg = m0 + cb + j*4;
        if (mg + 3 < N_) {
          const float4 x0 = *(const float4*)(r0 + j*4);
          const float4 x1 = *(const float4*)(r1 + j*4);
          va[j*4+0]=x0.x; va[j*4+1]=x0.y; va[j*4+2]=x0.z; va[j*4+3]=x0.w;
          vb[j*4+0]=x1.x; vb[j*4+1]=x1.y; vb[j*4+2]=x1.z; vb[j*4+3]=x1.w;
        } else {
          #pragma unroll
          for (int e = 0; e < 4; ++e) {
            const bool ok = (mg + e) < N_;
            va[j*4+e] = ok ? r0[j*4+e] : 0.f;
            vb[j*4+e] = ok ? r1[j*4+e] : 0.f;
          }
        }
      }
      #pragma unroll
      for (int e = 0; e < 8; ++e) {
        if (!rv0) va[e] = 0.f;
        if (!rv1) vb[e] = 0.f;
      }
    }
    // ---- hidden tile [32 n][128 c] -> regs (row-masked)
    float ha[8], hb[8];
    {
      const float* r0 = hbase + nc0*(T_*D_) + cb;
      const float* r1 = hbase + nc1*(T_*D_) + cb;
      const float4 x0a = *(const float4*)(r0);
      const float4 x0b = *(const float4*)(r0 + 4);
      const float4 x1a = *(const float4*)(r1);
      const float4 x1b = *(const float4*)(r1 + 4);
      ha[0]=x0a.x; ha[1]=x0a.y; ha[2]=x0a.z; ha[3]=x0a.w;
      ha[4]=x0b.x; ha[5]=x0b.y; ha[6]=x0b.z; ha[7]=x0b.w;
      hb[0]=x1a.x; hb[1]=x1a.y; hb[2]=x1a.z; hb[3]=x1a.w;
      hb[4]=x1b.x; hb[5]=x1b.y; hb[6]=x1b.z; hb[7]=x1b.w;
      #pragma unroll
      for (int e = 0; e < 8; ++e) {
        if (!rv0) ha[e] = 0.f;
        if (!rv1) hb[e] = 0.f;
      }
    }
    __syncthreads();   // protect previous chunk's fragment reads
    #pragma unroll
    for (int e = 0; e < 8; ++e)
      Ms32[(cb + e)*20 + (tid & 15)] = packbf2(va[e], vb[e]);
    #pragma unroll
    for (int e = 0; e < 8; ++e)
      Hs32[(cb + e)*20 + (tid & 15)] = packbf2(ha[e], hb[e]);
    __syncthreads();
    // ---- MFMA on staged tiles
    s16x8 af0 = *(const s16x8*)(Ms16 + (size_t)(w*32 +  0 + lr)*40 + lg*8);
    s16x8 af1 = *(const s16x8*)(Ms16 + (size_t)(w*32 + 16 + lr)*40 + lg*8);
    #pragma unroll
    for (int nt = 0; nt < 8; ++nt) {
      const s16x8 bf = *(const s16x8*)(Hs16 + (size_t)(nt*16 + lr)*40 + lg*8);
      acc1[0][nt] = MFMA16(af0, bf, acc1[0][nt]);
      acc1[1][nt] = MFMA16(af1, bf, acc1[1][nt]);
    }
  }

  // ---- phase 2: gcn = agg @ Wgcn^T + bgcn
  __syncthreads();   // all phase-1 LDS reads done before Gs overwrites
  unsigned short* gs = GsAll + (size_t)w * (32*136);
  #pragma unroll
  for (int nt = 0; nt < 8; nt++)
    #pragma unroll
    for (int mt = 0; mt < 2; mt++)
      #pragma unroll
      for (int r = 0; r < 4; r++)
        gs[(mt*16 + lg*4 + r)*136 + nt*16 + lr] = f2bfu(acc1[mt][nt][r]);

  f32x4 acc2[2][8];
  #pragma unroll
  for (int mt = 0; mt < 2; mt++)
    #pragma unroll
    for (int nt = 0; nt < 8; nt++)
      #pragma unroll
      for (int e = 0; e < 4; e++) acc2[mt][nt][e] = 0.f;

  #pragma unroll
  for (int ks = 0; ks < 4; ++ks) {
    const s16x8 a0 = *(const s16x8*)(gs + (size_t)( 0 + lr)*136 + ks*32 + lg*8);
    const s16x8 a1 = *(const s16x8*)(gs + (size_t)(16 + lr)*136 + ks*32 + lg*8);
    #pragma unroll
    for (int nt = 0; nt < 8; ++nt) {
      const s16x8 bf = *(const s16x8*)(Wgcnb + (size_t)(nt*16 + lr)*D_ + ks*32 + lg*8);
      acc2[0][nt] = MFMA16(a0, bf, acc2[0][nt]);
      acc2[1][nt] = MFMA16(a1, bf, acc2[1][nt]);
    }
  }

  // masked, strided epilogue (output rows stride T_*D_ in gcn layout [b,m,t,c])
  #pragma unroll
  for (int nt = 0; nt < 8; nt++) {
    const float bsc = bgcn[nt*16 + lr];
    #pragma unroll
    for (int mt = 0; mt < 2; mt++)
      #pragma unroll
      for (int r = 0; r < 4; r++)
        gs[(mt*16 + lg*4 + r)*136 + nt*16 + lr] = f2bfu(acc2[mt][nt][r] + bsc);
  }
  const size_t Obase = ((size_t)b*N_ + (m0 + w*32))*(size_t)(T_*D_) + (size_t)t*D_;
  #pragma unroll
  for (int p = 0; p < 8; p++) {
    const int c = p*64 + l;
    const int row = c >> 4, c8 = (c & 15) * 8;
    const int gm = m0 + w*32 + row;
    if (gm < N_) {
      const s16x8 v = *(const s16x8*)(gs + row*136 + c8);
      *(s16x8*)(gcn + Obase + (size_t)row*(T_*D_) + c8) = v;
    }
  }
}

// ---------------------------------------------------------------------------
// QKV: [MROWS,128] fp32 hidden -> Q,K,V bf16 via 3 fused MFMA GEMMs.
// ---------------------------------------------------------------------------
__global__ __launch_bounds__(256) void k_qkv(
    const float* __restrict__ hidden,
    const unsigned short* __restrict__ Wqb, const unsigned short* __restrict__ Wkb,
    const unsigned short* __restrict__ Wvb,
    const float* __restrict__ bq, const float* __restrict__ bk,
    const float* __restrict__ bv,
    unsigned short* __restrict__ Q, unsigned short* __restrict__ K,
    unsigned short* __restrict__ V)
{
  __shared__ __align__(16) unsigned short lbuf[4][32*136];
  const int tid = threadIdx.x;
  const int w = tid >> 6, l = tid & 63;
  const int lr = l & 15, lg = l >> 4;
  const size_t m0 = (size_t)blockIdx.x * 128 + w * 32;

  s16x8 afr[2][4];
  #pragma unroll
  for (int mt = 0; mt < 2; mt++)
    #pragma unroll
    for (int ks = 0; ks < 4; ks++)
      afr[mt][ks] = fragA_from_f32(hidden + (m0 + mt*16 + lr)*D_ + ks*32 + lg*8);

  const unsigned short* Ws[3] = {Wqb, Wkb, Wvb};
  const float*          bs[3] = {bq, bk, bv};
  unsigned short*       Os[3] = {Q, K, V};
  #pragma unroll
  for (int out = 0; out < 3; out++) {
    const unsigned short* W = Ws[out];
    f32x4 acc[2][8];
    #pragma unroll
    for (int mt = 0; mt < 2; mt++)
      #pragma unroll
      for (int nt = 0; nt < 8; nt++)
        #pragma unroll
        for (int e = 0; e < 4; e++) acc[mt][nt][e] = 0.f;
    #pragma unroll
    for (int ks = 0; ks < 4; ks++) {
      #pragma unroll
      for (int nt = 0; nt < 8; nt++) {
        const s16x8 bf = *(const s16x8*)(W + (size_t)(nt*16 + lr)*D_ + ks*32 + lg*8);
        acc[0][nt] = MFMA16(afr[0][ks], bf, acc[0][nt]);
        acc[1][nt] = MFMA16(afr[1][ks], bf, acc[1][nt]);
      }
    }
    epi_store_bf16(acc, bs[out], Os[out] + m0*D_, lbuf[w], l);
  }
}

// ---------------------------------------------------------------------------
// Generic projection GEMM: Out[M,128] = A[M,KSRC*128] @ Wb^T + bias.
// ---------------------------------------------------------------------------
template<int KSRC, bool OUTF32>
__global__ __launch_bounds__(256) void k_proj(
    const unsigned short* __restrict__ A0, const unsigned short* __restrict__ A1,
    const unsigned short* __restrict__ Wb, const float* __restrict__ bias,
    void* __restrict__ OutP)
{
  __shared__ __align__(16) unsigned short lbuf[4][32*136];
  const int tid = threadIdx.x;
  const int w = tid >> 6, l = tid & 63;
  const int lr = l & 15, lg = l >> 4;
  const size_t m0 = (size_t)blockIdx.x * 128 + w * 32;
  const int KW = KSRC * 128;

  f32x4 acc[2][8];
  #pragma unroll
  for (int mt = 0; mt < 2; mt++)
    #pragma unroll
    for (int nt = 0; nt < 8; nt++)
      #pragma unroll
      for (int e = 0; e < 4; e++) acc[mt][nt][e] = 0.f;

  #pragma unroll
  for (int ks = 0; ks < KSRC*4; ks++) {
    const unsigned short* Asrc = (KSRC == 2 && ks >= 4) ? A1 : A0;
    const int kk = (KSRC == 2 && ks >= 4) ? ks - 4 : ks;
    const s16x8 a0 = *(const s16x8*)(Asrc + (m0 +  0 + lr)*D_ + kk*32 + lg*8);
    const s16x8 a1 = *(const s16x8*)(Asrc + (m0 + 16 + lr)*D_ + kk*32 + lg*8);
    #pragma unroll
    for (int nt = 0; nt < 8; nt++) {
      const s16x8 bf = *(const s16x8*)(Wb + (size_t)(nt*16 + lr)*KW + ks*32 + lg*8);
      acc[0][nt] = MFMA16(a0, bf, acc[0][nt]);
      acc[1][nt] = MFMA16(a1, bf, acc[1][nt]);
    }
  }

  if (OUTF32) {
    float* Out = (float*)OutP;
    #pragma unroll
    for (int nt = 0; nt < 8; nt++) {
      const float b = bias[nt*16 + lr];
      #pragma unroll
      for (int mt = 0; mt < 2; mt++)
        #pragma unroll
        for (int r = 0; r < 4; r++)
          Out[(m0 + mt*16 + lg*4 + r)*D_ + nt*16 + lr] = acc[mt][nt][r] + b;
    }
  } else {
    epi_store_bf16(acc, bias, (unsigned short*)OutP + m0*D_, lbuf[w], l);
  }
}

// ---------------------------------------------------------------------------
// Attention core: per (b,n), causal softmax(QK^T/4)@V on VALU. 192 thr=(h,t).
// ---------------------------------------------------------------------------
__global__ __launch_bounds__(192) void k_attn2(
    const unsigned short* __restrict__ Q, const unsigned short* __restrict__ K,
    const unsigned short* __restrict__ V, unsigned short* __restrict__ CTX)
{
  __shared__ __align__(16) unsigned short Qs[T_*D_], Ks[T_*D_], Vs[T_*D_];
  const int tid = threadIdx.x;
  const size_t base = (size_t)blockIdx.x * (T_*D_);
  for (int i = tid; i < (T_*D_)/8; i += 192) {
    ((int4*)Qs)[i] = ((const int4*)(Q + base))[i];
    ((int4*)Ks)[i] = ((const int4*)(K + base))[i];
    ((int4*)Vs)[i] = ((const int4*)(V + base))[i];
  }
  __syncthreads();

  const int h = tid / T_, t = tid % T_;
  const int hb = h * 16;
  float q[16];
  #pragma unroll
  for (int e = 0; e < 16; e++) q[e] = bfu2f(Qs[t*D_ + hb + e]);

  float p[T_];
  float mx = -1e30f;
  #pragma unroll
  for (int s = 0; s < T_; s++) {
    float d = 0.f;
    #pragma unroll
    for (int e = 0; e < 16; e++) d += q[e] * bfu2f(Ks[s*D_ + hb + e]);
    d *= 0.25f;
    d = (s <= t) ? d : -1e30f;
    p[s] = d;
    mx = fmaxf(mx, d);
  }
  float den = 0.f;
  #pragma unroll
  for (int s = 0; s < T_; s++) {
    float e = __expf(p[s] - mx);
    e = (s <= t) ? e : 0.f;
    p[s] = e;
    den += e;
  }
  const float rd = 1.f / den;
  float o[16];
  #pragma unroll
  for (int e = 0; e < 16; e++) o[e] = 0.f;
  #pragma unroll
  for (int s = 0; s < T_; s++) {
    const float ps = p[s];
    #pragma unroll
    for (int e = 0; e < 16; e++) o[e] += ps * bfu2f(Vs[s*D_ + hb + e]);
  }
  s16x8 r0, r1;
  #pragma unroll
  for (int e = 0; e < 8; e++) { r0[e] = (short)f2bfu(o[e]*rd); r1[e] = (short)f2bfu(o[8+e]*rd); }
  *(s16x8*)(CTX + base + (size_t)t*D_ + hb)     = r0;
  *(s16x8*)(CTX + base + (size_t)t*D_ + hb + 8) = r1;
}

// ---------------------------------------------------------------------------
// BN statistics (deterministic two-stage) + final blend
// ---------------------------------------------------------------------------
__global__ __launch_bounds__(256) void k_bnstats(
    const float* __restrict__ g, float* __restrict__ psum, float* __restrict__ psq)
{
  const int tid = threadIdx.x;
  const int ch = tid & 127, sub = tid >> 7;
  const size_t r0 = (size_t)blockIdx.x * BN_ROWS;
  size_t r1 = r0 + BN_ROWS; if (r1 > (size_t)MROWS) r1 = (size_t)MROWS;
  float s = 0.f, q = 0.f;
  for (size_t r = r0 + sub; r < r1; r += 2) {
    const float x = g[r*D_ + ch];
    s += x; q += x*x;
  }
  __shared__ float ls[256], lq[256];
  ls[tid] = s; lq[tid] = q;
  __syncthreads();
  if (tid < 128) {
    psum[(size_t)blockIdx.x*128 + tid] = ls[tid] + ls[tid+128];
    psq [(size_t)blockIdx.x*128 + tid] = lq[tid] + lq[tid+128];
  }
}

__global__ __launch_bounds__(128) void k_bnfinal(
    const float* __restrict__ psum, const float* __restrict__ psq,
    float* __restrict__ meanv, float* __restrict__ invstdv)
{
  const int ch = threadIdx.x;
  float s = 0.f, q = 0.f;
  for (int i = 0; i < NBLK_BN; i++) { s += psum[(size_t)i*128 + ch]; q += psq[(size_t)i*128 + ch]; }
  const float mean = s / (float)MROWS;
  const float var  = q / (float)MROWS - mean*mean;
  meanv[ch] = mean;
  invstdv[ch] = rsqrtf(var + EPS_);
}

__global__ __launch_bounds__(256) void k_final(
    float* __restrict__ g,
    const unsigned short* __restrict__ gcn, const unsigned short* __restrict__ attn,
    const float* __restrict__ meanv, const float* __restrict__ invstdv,
    const float* __restrict__ gamma, const float* __restrict__ beta)
{
  const size_t tot4 = SELEMS >> 2;
  for (size_t i4 = (size_t)blockIdx.x*blockDim.x + threadIdx.x; i4 < tot4;
       i4 += (size_t)gridDim.x*blockDim.x) {
    const int c4 = (int)(i4 & 31) * 4;
    const float4 gv = ((const float4*)g)[i4];
    const ushort4 gc = ((const ushort4*)gcn)[i4];
    const ushort4 at = ((const ushort4*)attn)[i4];
    const float4 m4 = *(const float4*)(meanv + c4);
    const float4 s4 = *(const float4*)(invstdv + c4);
    const float4 ga = *(const float4*)(gamma + c4);
    const float4 be = *(const float4*)(beta + c4);
    float4 outv;
    { const float y = (gv.x - m4.x)*s4.x*ga.x + be.x;
      const float z = 1.f/(1.f + __expf(-y));
      outv.x = z*bfu2f(gc.x) + (1.f - z)*bfu2f(at.x); }
    { const float y = (gv.y - m4.y)*s4.y*ga.y + be.y;
      const float z = 1.f/(1.f + __expf(-y));
      outv.y = z*bfu2f(gc.y) + (1.f - z)*bfu2f(at.y); }
    { const float y = (gv.z - m4.z)*s4.z*ga.z + be.z;
      const float z = 1.f/(1.f + __expf(-y));
      outv.z = z*bfu2f(gc.z) + (1.f - z)*bfu2f(at.z); }
    { const float y = (gv.w - m4.w)*s4.w*ga.w + be.w;
      const float z = 1.f/(1.f + __expf(-y));
      outv.w = z*bfu2f(gc.w) + (1.f - z)*bfu2f(at.w); }
    ((float4*)g)[i4] = outv;
  }
}

// ---------------------------------------------------------------------------
extern "C" void kernel_launch(void* const* d_in, const int* in_sizes, int n_in,
                              void* d_out, int out_size, void* d_ws, size_t ws_size,
                              hipStream_t stream)
{
  (void)in_sizes; (void)n_in; (void)out_size; (void)ws_size;
  const float* hidden = (const float*)d_in[0];
  const float* matrix = (const float*)d_in[1];
  const float* Wq   = (const float*)d_in[2];  const float* bq    = (const float*)d_in[3];
  const float* Wk   = (const float*)d_in[4];  const float* bk    = (const float*)d_in[5];
  const float* Wv   = (const float*)d_in[6];  const float* bv    = (const float*)d_in[7];
  const float* Wo   = (const float*)d_in[8];  const float* bo    = (const float*)d_in[9];
  const float* Wgcn = (const float*)d_in[10]; const float* bgcn  = (const float*)d_in[11];
  const float* Wgate= (const float*)d_in[12]; const float* bgate = (const float*)d_in[13];
  const float* gamma= (const float*)d_in[14]; const float* beta  = (const float*)d_in[15];
  float* out = (float*)d_out;

  // ws (155.7 MiB): weights bf16 | X1 bf16[SELEMS] | X2 bf16[SELEMS] | stats
  unsigned short* WB = (unsigned short*)d_ws;
  unsigned short* Wqb    = WB;
  unsigned short* Wkb    = WB + 16384;
  unsigned short* Wvb    = WB + 32768;
  unsigned short* Wob    = WB + 49152;
  unsigned short* Wgcnb  = WB + 65536;
  unsigned short* Wgateb = WB + 81920;          // 32768 elems
  unsigned short* X1     = WB + 114688;
  unsigned short* X2     = X1 + SELEMS;
  float* psum    = (float*)(X2 + SELEMS);
  float* psq     = psum + (size_t)NBLK_BN*128;
  float* meanv   = psq  + (size_t)NBLK_BN*128;
  float* invstdv = meanv + 128;

  // d_out as bf16 scratch until the gate GEMM: D1 = lo half, D2 = hi half
  unsigned short* D1 = (unsigned short*)d_out;
  unsigned short* D2 = D1 + SELEMS;

  k_wcast<<<112, 256, 0, stream>>>(Wq, Wk, Wv, Wo, Wgcn, Wgate, WB);
  k_gcn2 <<<dim3(2, B_*T_), 256, 0, stream>>>(hidden, matrix, Wgcnb, bgcn, X2); // gcn -> X2
  k_qkv  <<<MROWS/128, 256, 0, stream>>>(hidden, Wqb, Wkb, Wvb, bq, bk, bv,
                                         D1, D2, X1);                    // Q,K,V
  k_attn2<<<B_*N_, 192, 0, stream>>>(D1, D2, X1, D1);                    // ctx over Q
  k_proj<1,false><<<MROWS/128, 256, 0, stream>>>(D1, nullptr, Wob, bo, X1);      // attn -> X1
  k_proj<2,true ><<<MROWS/128, 256, 0, stream>>>(X2, X1, Wgateb, bgate, (void*)out); // g -> d_out
  k_bnstats<<<NBLK_BN, 256, 0, stream>>>(out, psum, psq);
  k_bnfinal<<<1, 128, 0, stream>>>(psum, psq, meanv, invstdv);
  k_final<<<2048, 256, 0, stream>>>(out, X2, X1, meanv, invstdv, gamma, beta);
}

// Round 6
// 857.388 us; speedup vs baseline: 2.3949x; 1.1374x over previous
//
#include <hip/hip_runtime.h>

#define B_ 64
#define N_ 207
#define T_ 24
#define D_ 128
#define H_ 8
#define MROWS (B_*N_*T_)             // 317952 = 128*2484
#define SELEMS ((size_t)MROWS * D_)  // 40697856
#define NBLK_FB 768                  // fallback bnstats blocks; 768*414 = MROWS
#define BNROWS_FB 414
#define NBLK_FUSED (MROWS/128)       // 2484 gate tiles
#define EPS_ 1e-5f

typedef __attribute__((ext_vector_type(8))) short s16x8;   // 8 bf16 (4 VGPR)
typedef __attribute__((ext_vector_type(4))) float f32x4;   // MFMA acc

#define MFMA16(a,b,c) __builtin_amdgcn_mfma_f32_16x16x32_bf16(a,b,c,0,0,0)

__device__ __forceinline__ float bfu2f(unsigned short u) {
  return __uint_as_float(((unsigned int)u) << 16);
}
__device__ __forceinline__ unsigned short f2bfu(float f) {
  unsigned int x = __float_as_uint(f);
  return (unsigned short)((x + 0x7fffu + ((x >> 16) & 1u)) >> 16);  // RNE
}
__device__ __forceinline__ unsigned int packbf2(float lo, float hi) {
  return (unsigned int)f2bfu(lo) | ((unsigned int)f2bfu(hi) << 16);
}

__device__ __forceinline__ s16x8 fragA_from_f32(const float* __restrict__ p) {
  const float4 a = *(const float4*)p;
  const float4 b = *(const float4*)(p + 4);
  s16x8 r;
  r[0] = (short)f2bfu(a.x); r[1] = (short)f2bfu(a.y);
  r[2] = (short)f2bfu(a.z); r[3] = (short)f2bfu(a.w);
  r[4] = (short)f2bfu(b.x); r[5] = (short)f2bfu(b.y);
  r[6] = (short)f2bfu(b.z); r[7] = (short)f2bfu(b.w);
  return r;
}

// Epilogue: acc[2 Mtiles][8 Ntiles] (+bias) -> bf16 via per-wave LDS repack.
// C/D layout: col = lane&15, row = (lane>>4)*4 + reg  [m89/m91 verified].
__device__ __forceinline__ void epi_store_bf16(
    const f32x4 acc[2][8], const float* __restrict__ bias,
    unsigned short* __restrict__ Obase, unsigned short* __restrict__ lb, int l)
{
  const int lr = l & 15, lg = l >> 4;
  #pragma unroll
  for (int nt = 0; nt < 8; nt++) {
    const float b = bias[nt*16 + lr];
    #pragma unroll
    for (int mt = 0; mt < 2; mt++)
      #pragma unroll
      for (int r = 0; r < 4; r++)
        lb[(mt*16 + lg*4 + r)*136 + nt*16 + lr] = f2bfu(acc[mt][nt][r] + b);
  }
  #pragma unroll
  for (int p = 0; p < 8; p++) {
    const int c = p*64 + l;                      // 0..511
    const int row = c >> 4, c8 = (c & 15) * 8;   // 32 rows x 16 groups
    const s16x8 v = *(const s16x8*)&lb[row*136 + c8];
    *(s16x8*)(Obase + (size_t)row*D_ + c8) = v;
  }
}

// ---------------------------------------------------------------------------
// Weight cast: Wq|Wk|Wv|Wo|Wgcn (128x128 each) | Wgate (128x256) -> bf16
// ---------------------------------------------------------------------------
__global__ __launch_bounds__(256) void k_wcast(
    const float* __restrict__ Wq, const float* __restrict__ Wk,
    const float* __restrict__ Wv, const float* __restrict__ Wo,
    const float* __restrict__ Wgcn, const float* __restrict__ Wgate,
    unsigned short* __restrict__ out)
{
  const int idx4 = (blockIdx.x * 256 + threadIdx.x) * 4;
  if (idx4 >= 114688) return;
  const float* src; int off;
  if      (idx4 < 16384) { src = Wq;    off = idx4; }
  else if (idx4 < 32768) { src = Wk;    off = idx4 - 16384; }
  else if (idx4 < 49152) { src = Wv;    off = idx4 - 32768; }
  else if (idx4 < 65536) { src = Wo;    off = idx4 - 49152; }
  else if (idx4 < 81920) { src = Wgcn;  off = idx4 - 65536; }
  else                   { src = Wgate; off = idx4 - 81920; }
  const float4 v = *(const float4*)(src + off);
  ushort4 u;
  u.x = f2bfu(v.x); u.y = f2bfu(v.y); u.z = f2bfu(v.z); u.w = f2bfu(v.w);
  *(ushort4*)(out + idx4) = u;
}

// ---------------------------------------------------------------------------
// Fused GCN branch (MFMA): per (b,t): agg = M^T H (K=207), gcn = agg@Wgcn^T+b
// ---------------------------------------------------------------------------
__global__ __launch_bounds__(256) void k_gcn2(
    const float* __restrict__ hidden, const float* __restrict__ matrix,
    const unsigned short* __restrict__ Wgcnb, const float* __restrict__ bgcn,
    unsigned short* __restrict__ gcn)
{
  __shared__ __align__(16) unsigned char smem[34816];
  unsigned short* Ms16 = (unsigned short*)smem;            // [128 m][40 k]
  unsigned int*   Ms32 = (unsigned int*)smem;
  unsigned short* Hs16 = (unsigned short*)(smem + 10240);  // [128 c][40 k]
  unsigned int*   Hs32 = (unsigned int*)(smem + 10240);
  unsigned short* GsAll = (unsigned short*)smem;           // phase2: [4][32*136]

  const int tid = threadIdx.x;
  const int w = tid >> 6, l = tid & 63;
  const int lr = l & 15, lg = l >> 4;
  const int m0 = blockIdx.x * 128;
  const int by = (int)blockIdx.y;
  const int b = by / T_, t = by % T_;

  const int nn = (tid & 15) * 2;
  const int cb = (tid >> 4) * 8;

  const float* mbase = matrix + (size_t)(b*T_ + t)*N_*N_;
  const float* hbase = hidden + (size_t)b*N_*T_*D_ + (size_t)t*D_;

  f32x4 acc1[2][8];
  #pragma unroll
  for (int mt = 0; mt < 2; mt++)
    #pragma unroll
    for (int nt = 0; nt < 8; nt++)
      #pragma unroll
      for (int e = 0; e < 4; e++) acc1[mt][nt][e] = 0.f;

  for (int ch = 0; ch < 7; ++ch) {
    const int n0 = ch * 32;
    const int n_r0 = n0 + nn, n_r1 = n_r0 + 1;
    const bool rv0 = (n_r0 < N_), rv1 = (n_r1 < N_);
    const size_t nc0 = (size_t)(rv0 ? n_r0 : 0);
    const size_t nc1 = (size_t)(rv1 ? n_r1 : 0);

    float va[8], vb[8];
    {
      const float* r0 = mbase + nc0*N_ + m0 + cb;
      const float* r1 = mbase + nc1*N_ + m0 + cb;
      #pragma unroll
      for (int j = 0; j < 2; ++j) {
        const int mg = m0 + cb + j*4;
        if (mg + 3 < N_) {
          const float4 x0 = *(const float4*)(r0 + j*4);
          const float4 x1 = *(const float4*)(r1 + j*4);
          va[j*4+0]=x0.x; va[j*4+1]=x0.y; va[j*4+2]=x0.z; va[j*4+3]=x0.w;
          vb[j*4+0]=x1.x; vb[j*4+1]=x1.y; vb[j*4+2]=x1.z; vb[j*4+3]=x1.w;
        } else {
          #pragma unroll
          for (int e = 0; e < 4; ++e) {
            const bool ok = (mg + e) < N_;
            va[j*4+e] = ok ? r0[j*4+e] : 0.f;
            vb[j*4+e] = ok ? r1[j*4+e] : 0.f;
          }
        }
      }
      #pragma unroll
      for (int e = 0; e < 8; ++e) {
        if (!rv0) va[e] = 0.f;
        if (!rv1) vb[e] = 0.f;
      }
    }
    float ha[8], hb[8];
    {
      const float* r0 = hbase + nc0*(T_*D_) + cb;
      const float* r1 = hbase + nc1*(T_*D_) + cb;
      const float4 x0a = *(const float4*)(r0);
      const float4 x0b = *(const float4*)(r0 + 4);
      const float4 x1a = *(const float4*)(r1);
      const float4 x1b = *(const float4*)(r1 + 4);
      ha[0]=x0a.x; ha[1]=x0a.y; ha[2]=x0a.z; ha[3]=x0a.w;
      ha[4]=x0b.x; ha[5]=x0b.y; ha[6]=x0b.z; ha[7]=x0b.w;
      hb[0]=x1a.x; hb[1]=x1a.y; hb[2]=x1a.z; hb[3]=x1a.w;
      hb[4]=x1b.x; hb[5]=x1b.y; hb[6]=x1b.z; hb[7]=x1b.w;
      #pragma unroll
      for (int e = 0; e < 8; ++e) {
        if (!rv0) ha[e] = 0.f;
        if (!rv1) hb[e] = 0.f;
      }
    }
    __syncthreads();
    #pragma unroll
    for (int e = 0; e < 8; ++e)
      Ms32[(cb + e)*20 + (tid & 15)] = packbf2(va[e], vb[e]);
    #pragma unroll
    for (int e = 0; e < 8; ++e)
      Hs32[(cb + e)*20 + (tid & 15)] = packbf2(ha[e], hb[e]);
    __syncthreads();
    s16x8 af0 = *(const s16x8*)(Ms16 + (size_t)(w*32 +  0 + lr)*40 + lg*8);
    s16x8 af1 = *(const s16x8*)(Ms16 + (size_t)(w*32 + 16 + lr)*40 + lg*8);
    #pragma unroll
    for (int nt = 0; nt < 8; ++nt) {
      const s16x8 bf = *(const s16x8*)(Hs16 + (size_t)(nt*16 + lr)*40 + lg*8);
      acc1[0][nt] = MFMA16(af0, bf, acc1[0][nt]);
      acc1[1][nt] = MFMA16(af1, bf, acc1[1][nt]);
    }
  }

  __syncthreads();
  unsigned short* gs = GsAll + (size_t)w * (32*136);
  #pragma unroll
  for (int nt = 0; nt < 8; nt++)
    #pragma unroll
    for (int mt = 0; mt < 2; mt++)
      #pragma unroll
      for (int r = 0; r < 4; r++)
        gs[(mt*16 + lg*4 + r)*136 + nt*16 + lr] = f2bfu(acc1[mt][nt][r]);

  f32x4 acc2[2][8];
  #pragma unroll
  for (int mt = 0; mt < 2; mt++)
    #pragma unroll
    for (int nt = 0; nt < 8; nt++)
      #pragma unroll
      for (int e = 0; e < 4; e++) acc2[mt][nt][e] = 0.f;

  #pragma unroll
  for (int ks = 0; ks < 4; ++ks) {
    const s16x8 a0 = *(const s16x8*)(gs + (size_t)( 0 + lr)*136 + ks*32 + lg*8);
    const s16x8 a1 = *(const s16x8*)(gs + (size_t)(16 + lr)*136 + ks*32 + lg*8);
    #pragma unroll
    for (int nt = 0; nt < 8; ++nt) {
      const s16x8 bf = *(const s16x8*)(Wgcnb + (size_t)(nt*16 + lr)*D_ + ks*32 + lg*8);
      acc2[0][nt] = MFMA16(a0, bf, acc2[0][nt]);
      acc2[1][nt] = MFMA16(a1, bf, acc2[1][nt]);
    }
  }

  #pragma unroll
  for (int nt = 0; nt < 8; nt++) {
    const float bsc = bgcn[nt*16 + lr];
    #pragma unroll
    for (int mt = 0; mt < 2; mt++)
      #pragma unroll
      for (int r = 0; r < 4; r++)
        gs[(mt*16 + lg*4 + r)*136 + nt*16 + lr] = f2bfu(acc2[mt][nt][r] + bsc);
  }
  const size_t Obase = ((size_t)b*N_ + (m0 + w*32))*(size_t)(T_*D_) + (size_t)t*D_;
  #pragma unroll
  for (int p = 0; p < 8; p++) {
    const int c = p*64 + l;
    const int row = c >> 4, c8 = (c & 15) * 8;
    const int gm = m0 + w*32 + row;
    if (gm < N_) {
      const s16x8 v = *(const s16x8*)(gs + row*136 + c8);
      *(s16x8*)(gcn + Obase + (size_t)row*(T_*D_) + c8) = v;
    }
  }
}

// ---------------------------------------------------------------------------
// QKV: [MROWS,128] fp32 hidden -> Q,K,V bf16 via 3 fused MFMA GEMMs.
// ---------------------------------------------------------------------------
__global__ __launch_bounds__(256) void k_qkv(
    const float* __restrict__ hidden,
    const unsigned short* __restrict__ Wqb, const unsigned short* __restrict__ Wkb,
    const unsigned short* __restrict__ Wvb,
    const float* __restrict__ bq, const float* __restrict__ bk,
    const float* __restrict__ bv,
    unsigned short* __restrict__ Q, unsigned short* __restrict__ K,
    unsigned short* __restrict__ V)
{
  __shared__ __align__(16) unsigned short lbuf[4][32*136];
  const int tid = threadIdx.x;
  const int w = tid >> 6, l = tid & 63;
  const int lr = l & 15, lg = l >> 4;
  const size_t m0 = (size_t)blockIdx.x * 128 + w * 32;

  s16x8 afr[2][4];
  #pragma unroll
  for (int mt = 0; mt < 2; mt++)
    #pragma unroll
    for (int ks = 0; ks < 4; ks++)
      afr[mt][ks] = fragA_from_f32(hidden + (m0 + mt*16 + lr)*D_ + ks*32 + lg*8);

  const unsigned short* Ws[3] = {Wqb, Wkb, Wvb};
  const float*          bs[3] = {bq, bk, bv};
  unsigned short*       Os[3] = {Q, K, V};
  #pragma unroll
  for (int out = 0; out < 3; out++) {
    const unsigned short* W = Ws[out];
    f32x4 acc[2][8];
    #pragma unroll
    for (int mt = 0; mt < 2; mt++)
      #pragma unroll
      for (int nt = 0; nt < 8; nt++)
        #pragma unroll
        for (int e = 0; e < 4; e++) acc[mt][nt][e] = 0.f;
    #pragma unroll
    for (int ks = 0; ks < 4; ks++) {
      #pragma unroll
      for (int nt = 0; nt < 8; nt++) {
        const s16x8 bf = *(const s16x8*)(W + (size_t)(nt*16 + lr)*D_ + ks*32 + lg*8);
        acc[0][nt] = MFMA16(afr[0][ks], bf, acc[0][nt]);
        acc[1][nt] = MFMA16(afr[1][ks], bf, acc[1][nt]);
      }
    }
    epi_store_bf16(acc, bs[out], Os[out] + m0*D_, lbuf[w], l);
  }
}

// ---------------------------------------------------------------------------
// Projection GEMM (Wo path): Out[M,128] = A[M,128] @ Wb^T + bias -> bf16
// ---------------------------------------------------------------------------
__global__ __launch_bounds__(256) void k_projWo(
    const unsigned short* __restrict__ A0,
    const unsigned short* __restrict__ Wb, const float* __restrict__ bias,
    unsigned short* __restrict__ OutP)
{
  __shared__ __align__(16) unsigned short lbuf[4][32*136];
  const int tid = threadIdx.x;
  const int w = tid >> 6, l = tid & 63;
  const int lr = l & 15, lg = l >> 4;
  const size_t m0 = (size_t)blockIdx.x * 128 + w * 32;

  f32x4 acc[2][8];
  #pragma unroll
  for (int mt = 0; mt < 2; mt++)
    #pragma unroll
    for (int nt = 0; nt < 8; nt++)
      #pragma unroll
      for (int e = 0; e < 4; e++) acc[mt][nt][e] = 0.f;

  #pragma unroll
  for (int ks = 0; ks < 4; ks++) {
    const s16x8 a0 = *(const s16x8*)(A0 + (m0 +  0 + lr)*D_ + ks*32 + lg*8);
    const s16x8 a1 = *(const s16x8*)(A0 + (m0 + 16 + lr)*D_ + ks*32 + lg*8);
    #pragma unroll
    for (int nt = 0; nt < 8; nt++) {
      const s16x8 bf = *(const s16x8*)(Wb + (size_t)(nt*16 + lr)*D_ + ks*32 + lg*8);
      acc[0][nt] = MFMA16(a0, bf, acc[0][nt]);
      acc[1][nt] = MFMA16(a1, bf, acc[1][nt]);
    }
  }
  epi_store_bf16(acc, bias, OutP + m0*D_, lbuf[w], l);
}

// ---------------------------------------------------------------------------
// Gate GEMM + optional fused BN partial stats.
// g = [gcn|attn] @ Wgate^T + bgate -> fp32 Out; per-block per-channel
// sum/sumsq -> psum/psq[bid*128+ch] (deterministic fixed-order reduce).
// ---------------------------------------------------------------------------
template<bool STATS>
__global__ __launch_bounds__(256) void k_gate(
    const unsigned short* __restrict__ A0, const unsigned short* __restrict__ A1,
    const unsigned short* __restrict__ Wb, const float* __restrict__ bias,
    float* __restrict__ Out, float* __restrict__ psum, float* __restrict__ psq)
{
  __shared__ float lbs[4*128], lbq[4*128];
  const int tid = threadIdx.x;
  const int w = tid >> 6, l = tid & 63;
  const int lr = l & 15, lg = l >> 4;
  const size_t m0 = (size_t)blockIdx.x * 128 + w * 32;

  f32x4 acc[2][8];
  #pragma unroll
  for (int mt = 0; mt < 2; mt++)
    #pragma unroll
    for (int nt = 0; nt < 8; nt++)
      #pragma unroll
      for (int e = 0; e < 4; e++) acc[mt][nt][e] = 0.f;

  #pragma unroll
  for (int ks = 0; ks < 8; ks++) {
    const unsigned short* Asrc = (ks >= 4) ? A1 : A0;
    const int kk = (ks >= 4) ? ks - 4 : ks;
    const s16x8 a0 = *(const s16x8*)(Asrc + (m0 +  0 + lr)*D_ + kk*32 + lg*8);
    const s16x8 a1 = *(const s16x8*)(Asrc + (m0 + 16 + lr)*D_ + kk*32 + lg*8);
    #pragma unroll
    for (int nt = 0; nt < 8; nt++) {
      const s16x8 bf = *(const s16x8*)(Wb + (size_t)(nt*16 + lr)*256 + ks*32 + lg*8);
      acc[0][nt] = MFMA16(a0, bf, acc[0][nt]);
      acc[1][nt] = MFMA16(a1, bf, acc[1][nt]);
    }
  }

  #pragma unroll
  for (int nt = 0; nt < 8; nt++) {
    const float b = bias[nt*16 + lr];
    float s = 0.f, q = 0.f;
    #pragma unroll
    for (int mt = 0; mt < 2; mt++)
      #pragma unroll
      for (int r = 0; r < 4; r++) {
        const float v = acc[mt][nt][r] + b;
        Out[(m0 + mt*16 + lg*4 + r)*D_ + nt*16 + lr] = v;
        if (STATS) { s += v; q += v*v; }
      }
    if (STATS) {
      // reduce over the 4 lane-groups (rows) -> full 32-row sums
      s += __shfl_xor(s, 16); s += __shfl_xor(s, 32);
      q += __shfl_xor(q, 16); q += __shfl_xor(q, 32);
      if (lg == 0) {
        lbs[w*128 + nt*16 + lr] = s;
        lbq[w*128 + nt*16 + lr] = q;
      }
    }
  }
  if (STATS) {
    __syncthreads();
    if (tid < 128) {
      const float ss = lbs[tid] + lbs[128 + tid] + lbs[256 + tid] + lbs[384 + tid];
      const float qq = lbq[tid] + lbq[128 + tid] + lbq[256 + tid] + lbq[384 + tid];
      psum[(size_t)blockIdx.x*128 + tid] = ss;
      psq [(size_t)blockIdx.x*128 + tid] = qq;
    }
  }
}

// ---------------------------------------------------------------------------
// Attention core: per (b,n), causal softmax(QK^T/4)@V on VALU. 192 thr=(h,t).
// ---------------------------------------------------------------------------
__global__ __launch_bounds__(192) void k_attn2(
    const unsigned short* __restrict__ Q, const unsigned short* __restrict__ K,
    const unsigned short* __restrict__ V, unsigned short* __restrict__ CTX)
{
  __shared__ __align__(16) unsigned short Qs[T_*D_], Ks[T_*D_], Vs[T_*D_];
  const int tid = threadIdx.x;
  const size_t base = (size_t)blockIdx.x * (T_*D_);
  for (int i = tid; i < (T_*D_)/8; i += 192) {
    ((int4*)Qs)[i] = ((const int4*)(Q + base))[i];
    ((int4*)Ks)[i] = ((const int4*)(K + base))[i];
    ((int4*)Vs)[i] = ((const int4*)(V + base))[i];
  }
  __syncthreads();

  const int h = tid / T_, t = tid % T_;
  const int hb = h * 16;
  float q[16];
  #pragma unroll
  for (int e = 0; e < 16; e++) q[e] = bfu2f(Qs[t*D_ + hb + e]);

  float p[T_];
  float mx = -1e30f;
  #pragma unroll
  for (int s = 0; s < T_; s++) {
    float d = 0.f;
    #pragma unroll
    for (int e = 0; e < 16; e++) d += q[e] * bfu2f(Ks[s*D_ + hb + e]);
    d *= 0.25f;
    d = (s <= t) ? d : -1e30f;
    p[s] = d;
    mx = fmaxf(mx, d);
  }
  float den = 0.f;
  #pragma unroll
  for (int s = 0; s < T_; s++) {
    float e = __expf(p[s] - mx);
    e = (s <= t) ? e : 0.f;
    p[s] = e;
    den += e;
  }
  const float rd = 1.f / den;
  float o[16];
  #pragma unroll
  for (int e = 0; e < 16; e++) o[e] = 0.f;
  #pragma unroll
  for (int s = 0; s < T_; s++) {
    const float ps = p[s];
    #pragma unroll
    for (int e = 0; e < 16; e++) o[e] += ps * bfu2f(Vs[s*D_ + hb + e]);
  }
  s16x8 r0, r1;
  #pragma unroll
  for (int e = 0; e < 8; e++) { r0[e] = (short)f2bfu(o[e]*rd); r1[e] = (short)f2bfu(o[8+e]*rd); }
  *(s16x8*)(CTX + base + (size_t)t*D_ + hb)     = r0;
  *(s16x8*)(CTX + base + (size_t)t*D_ + hb + 8) = r1;
}

// ---------------------------------------------------------------------------
// Fallback BN stats: 768 blocks, float4 channel loads, 8 row-subs.
// ---------------------------------------------------------------------------
__global__ __launch_bounds__(256) void k_bnstats(
    const float* __restrict__ g, float* __restrict__ psum, float* __restrict__ psq)
{
  const int tid = threadIdx.x;
  const int c4 = (tid & 31) * 4, sub = tid >> 5;
  const size_t r0 = (size_t)blockIdx.x * BNROWS_FB;
  float4 s = make_float4(0.f,0.f,0.f,0.f), q = make_float4(0.f,0.f,0.f,0.f);
  for (int i = sub; i < BNROWS_FB; i += 8) {
    const float4 x = *(const float4*)(g + (r0 + i)*D_ + c4);
    s.x += x.x; s.y += x.y; s.z += x.z; s.w += x.w;
    q.x += x.x*x.x; q.y += x.y*x.y; q.z += x.z*x.z; q.w += x.w*x.w;
  }
  __shared__ float ls[8*128], lq[8*128];
  *(float4*)&ls[sub*128 + c4] = s;
  *(float4*)&lq[sub*128 + c4] = q;
  __syncthreads();
  if (tid < 128) {
    float ss = 0.f, qq = 0.f;
    #pragma unroll
    for (int k = 0; k < 8; k++) { ss += ls[k*128 + tid]; qq += lq[k*128 + tid]; }
    psum[(size_t)blockIdx.x*128 + tid] = ss;
    psq [(size_t)blockIdx.x*128 + tid] = qq;
  }
}

__global__ __launch_bounds__(1024) void k_bnfinal(
    const float* __restrict__ psum, const float* __restrict__ psq, int nblk,
    float* __restrict__ meanv, float* __restrict__ invstdv)
{
  const int tid = threadIdx.x;
  const int sub = tid >> 7, ch = tid & 127;
  float s = 0.f, q = 0.f;
  for (int i = sub; i < nblk; i += 8) {
    s += psum[(size_t)i*128 + ch];
    q += psq [(size_t)i*128 + ch];
  }
  __shared__ float ls[8*128], lq[8*128];
  ls[sub*128 + ch] = s; lq[sub*128 + ch] = q;
  __syncthreads();
  if (tid < 128) {
    float ss = 0.f, qq = 0.f;
    #pragma unroll
    for (int k = 0; k < 8; k++) { ss += ls[k*128 + tid]; qq += lq[k*128 + tid]; }
    const float mean = ss / (float)MROWS;
    const float var  = qq / (float)MROWS - mean*mean;
    meanv[tid] = mean;
    invstdv[tid] = rsqrtf(var + EPS_);
  }
}

__global__ __launch_bounds__(256) void k_final(
    float* __restrict__ g,
    const unsigned short* __restrict__ gcn, const unsigned short* __restrict__ attn,
    const float* __restrict__ meanv, const float* __restrict__ invstdv,
    const float* __restrict__ gamma, const float* __restrict__ beta)
{
  const size_t tot4 = SELEMS >> 2;
  for (size_t i4 = (size_t)blockIdx.x*blockDim.x + threadIdx.x; i4 < tot4;
       i4 += (size_t)gridDim.x*blockDim.x) {
    const int c4 = (int)(i4 & 31) * 4;
    const float4 gv = ((const float4*)g)[i4];
    const ushort4 gc = ((const ushort4*)gcn)[i4];
    const ushort4 at = ((const ushort4*)attn)[i4];
    const float4 m4 = *(const float4*)(meanv + c4);
    const float4 s4 = *(const float4*)(invstdv + c4);
    const float4 ga = *(const float4*)(gamma + c4);
    const float4 be = *(const float4*)(beta + c4);
    float4 outv;
    { const float y = (gv.x - m4.x)*s4.x*ga.x + be.x;
      const float z = 1.f/(1.f + __expf(-y));
      outv.x = z*bfu2f(gc.x) + (1.f - z)*bfu2f(at.x); }
    { const float y = (gv.y - m4.y)*s4.y*ga.y + be.y;
      const float z = 1.f/(1.f + __expf(-y));
      outv.y = z*bfu2f(gc.y) + (1.f - z)*bfu2f(at.y); }
    { const float y = (gv.z - m4.z)*s4.z*ga.z + be.z;
      const float z = 1.f/(1.f + __expf(-y));
      outv.z = z*bfu2f(gc.z) + (1.f - z)*bfu2f(at.z); }
    { const float y = (gv.w - m4.w)*s4.w*ga.w + be.w;
      const float z = 1.f/(1.f + __expf(-y));
      outv.w = z*bfu2f(gc.w) + (1.f - z)*bfu2f(at.w); }
    ((float4*)g)[i4] = outv;
  }
}

// ---------------------------------------------------------------------------
extern "C" void kernel_launch(void* const* d_in, const int* in_sizes, int n_in,
                              void* d_out, int out_size, void* d_ws, size_t ws_size,
                              hipStream_t stream)
{
  (void)in_sizes; (void)n_in; (void)out_size;
  const float* hidden = (const float*)d_in[0];
  const float* matrix = (const float*)d_in[1];
  const float* Wq   = (const float*)d_in[2];  const float* bq    = (const float*)d_in[3];
  const float* Wk   = (const float*)d_in[4];  const float* bk    = (const float*)d_in[5];
  const float* Wv   = (const float*)d_in[6];  const float* bv    = (const float*)d_in[7];
  const float* Wo   = (const float*)d_in[8];  const float* bo    = (const float*)d_in[9];
  const float* Wgcn = (const float*)d_in[10]; const float* bgcn  = (const float*)d_in[11];
  const float* Wgate= (const float*)d_in[12]; const float* bgate = (const float*)d_in[13];
  const float* gamma= (const float*)d_in[14]; const float* beta  = (const float*)d_in[15];
  float* out = (float*)d_out;

  // ws: weights bf16 | X1 bf16[SELEMS] | X2 bf16[SELEMS] | psum | psq | mean | invstd
  unsigned short* WB = (unsigned short*)d_ws;
  unsigned short* Wqb    = WB;
  unsigned short* Wkb    = WB + 16384;
  unsigned short* Wvb    = WB + 32768;
  unsigned short* Wob    = WB + 49152;
  unsigned short* Wgcnb  = WB + 65536;
  unsigned short* Wgateb = WB + 81920;          // 32768 elems
  unsigned short* X1     = WB + 114688;
  unsigned short* X2     = X1 + SELEMS;
  float* psum    = (float*)(X2 + SELEMS);

  // Fused-stats path needs psum/psq of NBLK_FUSED*128 each (~2.5 MB);
  // fall back to the 768-block standalone reduction if ws is too small.
  const size_t base_bytes = (size_t)(WB + 114688 - (unsigned short*)d_ws)*2
                          + 2*SELEMS*2;
  const size_t fused_bytes = base_bytes + ((size_t)NBLK_FUSED*128*2 + 256)*4;
  const bool fused = (ws_size >= fused_bytes);
  const int nblk = fused ? NBLK_FUSED : NBLK_FB;
  float* psq     = psum + (size_t)nblk*128;
  float* meanv   = psq  + (size_t)nblk*128;
  float* invstdv = meanv + 128;

  unsigned short* D1 = (unsigned short*)d_out;
  unsigned short* D2 = D1 + SELEMS;

  k_wcast<<<112, 256, 0, stream>>>(Wq, Wk, Wv, Wo, Wgcn, Wgate, WB);
  k_gcn2 <<<dim3(2, B_*T_), 256, 0, stream>>>(hidden, matrix, Wgcnb, bgcn, X2);
  k_qkv  <<<MROWS/128, 256, 0, stream>>>(hidden, Wqb, Wkb, Wvb, bq, bk, bv,
                                         D1, D2, X1);
  k_attn2<<<B_*N_, 192, 0, stream>>>(D1, D2, X1, D1);
  k_projWo<<<MROWS/128, 256, 0, stream>>>(D1, Wob, bo, X1);
  if (fused) {
    k_gate<true><<<MROWS/128, 256, 0, stream>>>(X2, X1, Wgateb, bgate, out, psum, psq);
  } else {
    k_gate<false><<<MROWS/128, 256, 0, stream>>>(X2, X1, Wgateb, bgate, out, psum, psq);
    k_bnstats<<<NBLK_FB, 256, 0, stream>>>(out, psum, psq);
  }
  k_bnfinal<<<1, 1024, 0, stream>>>(psum, psq, nblk, meanv, invstdv);
  k_final<<<2048, 256, 0, stream>>>(out, X2, X1, meanv, invstdv, gamma, beta);
}

// Round 7
// 815.594 us; speedup vs baseline: 2.5177x; 1.0512x over previous
//
#include <hip/hip_runtime.h>

#define B_ 64
#define N_ 207
#define T_ 24
#define D_ 128
#define H_ 8
#define MROWS (B_*N_*T_)             // 317952 = 128*2484
#define SELEMS ((size_t)MROWS * D_)  // 40697856
#define NBLK_FB 768
#define BNROWS_FB 414
#define NBLK_FUSED (MROWS/128)       // 2484 gate tiles
#define EPS_ 1e-5f

typedef __attribute__((ext_vector_type(8))) short s16x8;   // 8 bf16 (4 VGPR)
typedef __attribute__((ext_vector_type(4))) float f32x4;   // MFMA acc

#define MFMA16(a,b,c) __builtin_amdgcn_mfma_f32_16x16x32_bf16(a,b,c,0,0,0)

__device__ __forceinline__ float bfu2f(unsigned short u) {
  return __uint_as_float(((unsigned int)u) << 16);
}
__device__ __forceinline__ unsigned short f2bfu(float f) {
  unsigned int x = __float_as_uint(f);
  return (unsigned short)((x + 0x7fffu + ((x >> 16) & 1u)) >> 16);  // RNE
}
__device__ __forceinline__ unsigned int packbf2(float lo, float hi) {
  return (unsigned int)f2bfu(lo) | ((unsigned int)f2bfu(hi) << 16);
}

// ---------------------------------------------------------------------------
// Weight cast: Wq|Wk|Wv|Wo|Wgcn (128x128 each) | Wgate (128x256) -> bf16
// ---------------------------------------------------------------------------
__global__ __launch_bounds__(256) void k_wcast(
    const float* __restrict__ Wq, const float* __restrict__ Wk,
    const float* __restrict__ Wv, const float* __restrict__ Wo,
    const float* __restrict__ Wgcn, const float* __restrict__ Wgate,
    unsigned short* __restrict__ out)
{
  const int idx4 = (blockIdx.x * 256 + threadIdx.x) * 4;
  if (idx4 >= 114688) return;
  const float* src; int off;
  if      (idx4 < 16384) { src = Wq;    off = idx4; }
  else if (idx4 < 32768) { src = Wk;    off = idx4 - 16384; }
  else if (idx4 < 49152) { src = Wv;    off = idx4 - 32768; }
  else if (idx4 < 65536) { src = Wo;    off = idx4 - 49152; }
  else if (idx4 < 81920) { src = Wgcn;  off = idx4 - 65536; }
  else                   { src = Wgate; off = idx4 - 81920; }
  const float4 v = *(const float4*)(src + off);
  ushort4 u;
  u.x = f2bfu(v.x); u.y = f2bfu(v.y); u.z = f2bfu(v.z); u.w = f2bfu(v.w);
  *(ushort4*)(out + idx4) = u;
}

// ---------------------------------------------------------------------------
// GCN chunk loader: masked global->reg for matrix/hidden 32-n chunk `ch`.
// ---------------------------------------------------------------------------
__device__ __forceinline__ void gcn_load(
    const float* __restrict__ mbase, const float* __restrict__ hbase,
    int m0, int nn, int cb, int ch,
    float va[8], float vb[8], float ha[8], float hb[8])
{
  const int n_r0 = ch*32 + nn, n_r1 = n_r0 + 1;
  const bool rv0 = (n_r0 < N_), rv1 = (n_r1 < N_);
  const size_t nc0 = (size_t)(rv0 ? n_r0 : 0);
  const size_t nc1 = (size_t)(rv1 ? n_r1 : 0);
  {
    const float* r0 = mbase + nc0*N_ + m0 + cb;
    const float* r1 = mbase + nc1*N_ + m0 + cb;
    #pragma unroll
    for (int j = 0; j < 2; ++j) {
      const int mg = m0 + cb + j*4;
      if (mg + 3 < N_) {
        const float4 x0 = *(const float4*)(r0 + j*4);
        const float4 x1 = *(const float4*)(r1 + j*4);
        va[j*4+0]=x0.x; va[j*4+1]=x0.y; va[j*4+2]=x0.z; va[j*4+3]=x0.w;
        vb[j*4+0]=x1.x; vb[j*4+1]=x1.y; vb[j*4+2]=x1.z; vb[j*4+3]=x1.w;
      } else {
        #pragma unroll
        for (int e = 0; e < 4; ++e) {
          const bool ok = (mg + e) < N_;
          va[j*4+e] = ok ? r0[j*4+e] : 0.f;
          vb[j*4+e] = ok ? r1[j*4+e] : 0.f;
        }
      }
    }
    #pragma unroll
    for (int e = 0; e < 8; ++e) {
      if (!rv0) va[e] = 0.f;
      if (!rv1) vb[e] = 0.f;
    }
  }
  {
    const float* r0 = hbase + nc0*(T_*D_) + cb;
    const float* r1 = hbase + nc1*(T_*D_) + cb;
    const float4 x0a = *(const float4*)(r0);
    const float4 x0b = *(const float4*)(r0 + 4);
    const float4 x1a = *(const float4*)(r1);
    const float4 x1b = *(const float4*)(r1 + 4);
    ha[0]=x0a.x; ha[1]=x0a.y; ha[2]=x0a.z; ha[3]=x0a.w;
    ha[4]=x0b.x; ha[5]=x0b.y; ha[6]=x0b.z; ha[7]=x0b.w;
    hb[0]=x1a.x; hb[1]=x1a.y; hb[2]=x1a.z; hb[3]=x1a.w;
    hb[4]=x1b.x; hb[5]=x1b.y; hb[6]=x1b.z; hb[7]=x1b.w;
    #pragma unroll
    for (int e = 0; e < 8; ++e) {
      if (!rv0) ha[e] = 0.f;
      if (!rv1) hb[e] = 0.f;
    }
  }
}

// ---------------------------------------------------------------------------
// Fused GCN branch (MFMA, pipelined): per (b,t):
//   phase1: agg = M^T H (K=207, double-buffered LDS, ONE barrier per chunk)
//   phase2: gcn = agg @ Wgcn^T + bgcn
// ---------------------------------------------------------------------------
__global__ __launch_bounds__(256) void k_gcn2(
    const float* __restrict__ hidden, const float* __restrict__ matrix,
    const unsigned short* __restrict__ Wgcnb, const float* __restrict__ bgcn,
    unsigned short* __restrict__ gcn)
{
  __shared__ __align__(16) unsigned char smem[40960];  // 2 x (Ms 10240 + Hs 10240)
  unsigned short* GsAll = (unsigned short*)smem;       // phase2 overlap [0,34816)

  const int tid = threadIdx.x;
  const int w = tid >> 6, l = tid & 63;
  const int lr = l & 15, lg = l >> 4;
  const int m0 = blockIdx.x * 128;
  const int by = (int)blockIdx.y;
  const int b = by / T_, t = by % T_;

  const int nn = (tid & 15) * 2;
  const int cb = (tid >> 4) * 8;

  const float* mbase = matrix + (size_t)(b*T_ + t)*N_*N_;
  const float* hbase = hidden + (size_t)b*N_*T_*D_ + (size_t)t*D_;

  f32x4 acc1[2][8];
  #pragma unroll
  for (int mt = 0; mt < 2; mt++)
    #pragma unroll
    for (int nt = 0; nt < 8; nt++)
      #pragma unroll
      for (int e = 0; e < 4; e++) acc1[mt][nt][e] = 0.f;

  float va[8], vb[8], ha[8], hb[8];
  gcn_load(mbase, hbase, m0, nn, cb, 0, va, vb, ha, hb);

  #pragma unroll
  for (int ch = 0; ch < 7; ++ch) {
    unsigned char* base = smem + ((ch & 1) ? 20480 : 0);
    unsigned int* M32 = (unsigned int*)base;
    unsigned int* H32 = (unsigned int*)(base + 10240);
    #pragma unroll
    for (int e = 0; e < 8; ++e)
      M32[(cb + e)*20 + (tid & 15)] = packbf2(va[e], vb[e]);
    #pragma unroll
    for (int e = 0; e < 8; ++e)
      H32[(cb + e)*20 + (tid & 15)] = packbf2(ha[e], hb[e]);
    if (ch < 6)
      gcn_load(mbase, hbase, m0, nn, cb, ch + 1, va, vb, ha, hb);
    __syncthreads();
    const unsigned short* M16 = (const unsigned short*)M32;
    const unsigned short* H16 = (const unsigned short*)H32;
    const s16x8 af0 = *(const s16x8*)(M16 + (size_t)(w*32 +  0 + lr)*40 + lg*8);
    const s16x8 af1 = *(const s16x8*)(M16 + (size_t)(w*32 + 16 + lr)*40 + lg*8);
    #pragma unroll
    for (int nt = 0; nt < 8; ++nt) {
      const s16x8 bf = *(const s16x8*)(H16 + (size_t)(nt*16 + lr)*40 + lg*8);
      acc1[0][nt] = MFMA16(af0, bf, acc1[0][nt]);
      acc1[1][nt] = MFMA16(af1, bf, acc1[1][nt]);
    }
  }

  __syncthreads();   // all phase-1 reads done before GsAll overwrites
  unsigned short* gs = GsAll + (size_t)w * (32*136);
  #pragma unroll
  for (int nt = 0; nt < 8; nt++)
    #pragma unroll
    for (int mt = 0; mt < 2; mt++)
      #pragma unroll
      for (int r = 0; r < 4; r++)
        gs[(mt*16 + lg*4 + r)*136 + nt*16 + lr] = f2bfu(acc1[mt][nt][r]);

  f32x4 acc2[2][8];
  #pragma unroll
  for (int mt = 0; mt < 2; mt++)
    #pragma unroll
    for (int nt = 0; nt < 8; nt++)
      #pragma unroll
      for (int e = 0; e < 4; e++) acc2[mt][nt][e] = 0.f;

  #pragma unroll
  for (int ks = 0; ks < 4; ++ks) {
    const s16x8 a0 = *(const s16x8*)(gs + (size_t)( 0 + lr)*136 + ks*32 + lg*8);
    const s16x8 a1 = *(const s16x8*)(gs + (size_t)(16 + lr)*136 + ks*32 + lg*8);
    #pragma unroll
    for (int nt = 0; nt < 8; ++nt) {
      const s16x8 bf = *(const s16x8*)(Wgcnb + (size_t)(nt*16 + lr)*D_ + ks*32 + lg*8);
      acc2[0][nt] = MFMA16(a0, bf, acc2[0][nt]);
      acc2[1][nt] = MFMA16(a1, bf, acc2[1][nt]);
    }
  }

  #pragma unroll
  for (int nt = 0; nt < 8; nt++) {
    const float bsc = bgcn[nt*16 + lr];
    #pragma unroll
    for (int mt = 0; mt < 2; mt++)
      #pragma unroll
      for (int r = 0; r < 4; r++)
        gs[(mt*16 + lg*4 + r)*136 + nt*16 + lr] = f2bfu(acc2[mt][nt][r] + bsc);
  }
  const size_t Obase = ((size_t)b*N_ + (m0 + w*32))*(size_t)(T_*D_) + (size_t)t*D_;
  #pragma unroll
  for (int p = 0; p < 8; p++) {
    const int c = p*64 + l;
    const int row = c >> 4, c8 = (c & 15) * 8;
    const int gm = m0 + w*32 + row;
    if (gm < N_) {
      const s16x8 v = *(const s16x8*)(gs + row*136 + c8);
      *(s16x8*)(gcn + Obase + (size_t)row*(T_*D_) + c8) = v;
    }
  }
}

// ---------------------------------------------------------------------------
// Fused attention: per (b,n) block (256 thr = 4 waves):
//   X->LDS bf16; Q/K/V = X@W^T+b (MFMA, ->LDS); causal softmax (VALU);
//   ctx@Wo^T+bo (MFMA) -> attn_out bf16.  No global intermediates.
// ---------------------------------------------------------------------------
__global__ __launch_bounds__(256) void k_attn3(
    const float* __restrict__ hidden,
    const unsigned short* __restrict__ Wqb, const unsigned short* __restrict__ Wkb,
    const unsigned short* __restrict__ Wvb, const unsigned short* __restrict__ Wob,
    const float* __restrict__ bq, const float* __restrict__ bk,
    const float* __restrict__ bv, const float* __restrict__ bo,
    unsigned short* __restrict__ attnO)
{
  __shared__ __align__(16) unsigned short Xs[32*136], Qs[32*136],
                                          Ks[32*136], Vs[32*136];  // 34 KB
  const int tid = threadIdx.x;
  const int w = tid >> 6, l = tid & 63;
  const int lr = l & 15, lg = l >> 4;
  const size_t bn = blockIdx.x;
  const float* X = hidden + bn * (size_t)(T_*D_);

  // stage X -> Xs (bf16), rows 24..31 zero
  for (int i = tid; i < 32*16; i += 256) {
    const int row = i >> 4, g8 = (i & 15) * 8;
    s16x8 v;
    if (row < T_) {
      const float4 a  = *(const float4*)(X + (size_t)row*D_ + g8);
      const float4 b2 = *(const float4*)(X + (size_t)row*D_ + g8 + 4);
      v[0]=(short)f2bfu(a.x);  v[1]=(short)f2bfu(a.y);
      v[2]=(short)f2bfu(a.z);  v[3]=(short)f2bfu(a.w);
      v[4]=(short)f2bfu(b2.x); v[5]=(short)f2bfu(b2.y);
      v[6]=(short)f2bfu(b2.z); v[7]=(short)f2bfu(b2.w);
    } else {
      #pragma unroll
      for (int e = 0; e < 8; e++) v[e] = 0;
    }
    *(s16x8*)&Xs[row*136 + g8] = v;
  }
  __syncthreads();

  // A-frags (rows 0..31, shared across Q/K/V GEMMs)
  s16x8 af[2][4];
  #pragma unroll
  for (int mt = 0; mt < 2; mt++)
    #pragma unroll
    for (int ks = 0; ks < 4; ks++)
      af[mt][ks] = *(const s16x8*)&Xs[(mt*16 + lr)*136 + ks*32 + lg*8];

  // Q/K/V projections: wave w computes cols 32w..32w+31
  const unsigned short* Wp[3] = {Wqb, Wkb, Wvb};
  const float*          bp[3] = {bq, bk, bv};
  unsigned short*       Op[3] = {Qs, Ks, Vs};
  #pragma unroll
  for (int o = 0; o < 3; o++) {
    f32x4 acc[2][2];
    #pragma unroll
    for (int mt = 0; mt < 2; mt++)
      #pragma unroll
      for (int nt = 0; nt < 2; nt++)
        #pragma unroll
        for (int e = 0; e < 4; e++) acc[mt][nt][e] = 0.f;
    #pragma unroll
    for (int ks = 0; ks < 4; ks++) {
      #pragma unroll
      for (int nt = 0; nt < 2; nt++) {
        const s16x8 bf = *(const s16x8*)(Wp[o] + (size_t)(w*32 + nt*16 + lr)*D_ + ks*32 + lg*8);
        acc[0][nt] = MFMA16(af[0][ks], bf, acc[0][nt]);
        acc[1][nt] = MFMA16(af[1][ks], bf, acc[1][nt]);
      }
    }
    #pragma unroll
    for (int nt = 0; nt < 2; nt++) {
      const float bb = bp[o][w*32 + nt*16 + lr];
      #pragma unroll
      for (int mt = 0; mt < 2; mt++)
        #pragma unroll
        for (int r = 0; r < 4; r++)
          Op[o][(mt*16 + lg*4 + r)*136 + w*32 + nt*16 + lr] =
              f2bfu(acc[mt][nt][r] + bb);
    }
  }
  __syncthreads();

  // causal softmax(QK^T/4)@V, one thread per (h,t); ctx -> Qs (own row/cols)
  if (tid < H_*T_) {
    const int h = tid / T_, t = tid % T_;
    const int hb = h * 16;
    float q[16];
    {
      const s16x8 q0 = *(const s16x8*)&Qs[t*136 + hb];
      const s16x8 q1 = *(const s16x8*)&Qs[t*136 + hb + 8];
      #pragma unroll
      for (int e = 0; e < 8; e++) {
        q[e]   = bfu2f((unsigned short)q0[e]);
        q[8+e] = bfu2f((unsigned short)q1[e]);
      }
    }
    float p[T_];
    float mx = -1e30f;
    #pragma unroll
    for (int s = 0; s < T_; s++) {
      const s16x8 k0 = *(const s16x8*)&Ks[s*136 + hb];
      const s16x8 k1 = *(const s16x8*)&Ks[s*136 + hb + 8];
      float d = 0.f;
      #pragma unroll
      for (int e = 0; e < 8; e++) {
        d += q[e]   * bfu2f((unsigned short)k0[e]);
        d += q[8+e] * bfu2f((unsigned short)k1[e]);
      }
      d *= 0.25f;
      d = (s <= t) ? d : -1e30f;
      p[s] = d;
      mx = fmaxf(mx, d);
    }
    float den = 0.f;
    #pragma unroll
    for (int s = 0; s < T_; s++) {
      float e = __expf(p[s] - mx);
      e = (s <= t) ? e : 0.f;
      p[s] = e;
      den += e;
    }
    const float rd = 1.f / den;
    float o[16];
    #pragma unroll
    for (int e = 0; e < 16; e++) o[e] = 0.f;
    #pragma unroll
    for (int s = 0; s < T_; s++) {
      const float ps = p[s];
      const s16x8 v0 = *(const s16x8*)&Vs[s*136 + hb];
      const s16x8 v1 = *(const s16x8*)&Vs[s*136 + hb + 8];
      #pragma unroll
      for (int e = 0; e < 8; e++) {
        o[e]   += ps * bfu2f((unsigned short)v0[e]);
        o[8+e] += ps * bfu2f((unsigned short)v1[e]);
      }
    }
    s16x8 r0, r1;
    #pragma unroll
    for (int e = 0; e < 8; e++) {
      r0[e] = (short)f2bfu(o[e]   * rd);
      r1[e] = (short)f2bfu(o[8+e] * rd);
    }
    *(s16x8*)&Qs[t*136 + hb]     = r0;
    *(s16x8*)&Qs[t*136 + hb + 8] = r1;
  }
  __syncthreads();

  // Wo GEMM: A = ctx (Qs), repack into Xs, cooperative store rows<24
  s16x8 cf[2][4];
  #pragma unroll
  for (int mt = 0; mt < 2; mt++)
    #pragma unroll
    for (int ks = 0; ks < 4; ks++)
      cf[mt][ks] = *(const s16x8*)&Qs[(mt*16 + lr)*136 + ks*32 + lg*8];
  f32x4 acc2[2][2];
  #pragma unroll
  for (int mt = 0; mt < 2; mt++)
    #pragma unroll
    for (int nt = 0; nt < 2; nt++)
      #pragma unroll
      for (int e = 0; e < 4; e++) acc2[mt][nt][e] = 0.f;
  #pragma unroll
  for (int ks = 0; ks < 4; ks++) {
    #pragma unroll
    for (int nt = 0; nt < 2; nt++) {
      const s16x8 bf = *(const s16x8*)(Wob + (size_t)(w*32 + nt*16 + lr)*D_ + ks*32 + lg*8);
      acc2[0][nt] = MFMA16(cf[0][ks], bf, acc2[0][nt]);
      acc2[1][nt] = MFMA16(cf[1][ks], bf, acc2[1][nt]);
    }
  }
  #pragma unroll
  for (int nt = 0; nt < 2; nt++) {
    const float bb = bo[w*32 + nt*16 + lr];
    #pragma unroll
    for (int mt = 0; mt < 2; mt++)
      #pragma unroll
      for (int r = 0; r < 4; r++)
        Xs[(mt*16 + lg*4 + r)*136 + w*32 + nt*16 + lr] =
            f2bfu(acc2[mt][nt][r] + bb);
  }
  __syncthreads();
  unsigned short* O = attnO + bn * (size_t)(T_*D_);
  for (int i = tid; i < 24*16; i += 256) {
    const int row = i >> 4, g8 = (i & 15) * 8;
    *(s16x8*)(O + (size_t)row*D_ + g8) = *(const s16x8*)&Xs[row*136 + g8];
  }
}

// ---------------------------------------------------------------------------
// Gate GEMM + optional fused BN partial stats.
// ---------------------------------------------------------------------------
template<bool STATS>
__global__ __launch_bounds__(256) void k_gate(
    const unsigned short* __restrict__ A0, const unsigned short* __restrict__ A1,
    const unsigned short* __restrict__ Wb, const float* __restrict__ bias,
    float* __restrict__ Out, float* __restrict__ psum, float* __restrict__ psq)
{
  __shared__ float lbs[4*128], lbq[4*128];
  const int tid = threadIdx.x;
  const int w = tid >> 6, l = tid & 63;
  const int lr = l & 15, lg = l >> 4;
  const size_t m0 = (size_t)blockIdx.x * 128 + w * 32;

  f32x4 acc[2][8];
  #pragma unroll
  for (int mt = 0; mt < 2; mt++)
    #pragma unroll
    for (int nt = 0; nt < 8; nt++)
      #pragma unroll
      for (int e = 0; e < 4; e++) acc[mt][nt][e] = 0.f;

  #pragma unroll
  for (int ks = 0; ks < 8; ks++) {
    const unsigned short* Asrc = (ks >= 4) ? A1 : A0;
    const int kk = (ks >= 4) ? ks - 4 : ks;
    const s16x8 a0 = *(const s16x8*)(Asrc + (m0 +  0 + lr)*D_ + kk*32 + lg*8);
    const s16x8 a1 = *(const s16x8*)(Asrc + (m0 + 16 + lr)*D_ + kk*32 + lg*8);
    #pragma unroll
    for (int nt = 0; nt < 8; nt++) {
      const s16x8 bf = *(const s16x8*)(Wb + (size_t)(nt*16 + lr)*256 + ks*32 + lg*8);
      acc[0][nt] = MFMA16(a0, bf, acc[0][nt]);
      acc[1][nt] = MFMA16(a1, bf, acc[1][nt]);
    }
  }

  #pragma unroll
  for (int nt = 0; nt < 8; nt++) {
    const float b = bias[nt*16 + lr];
    float s = 0.f, q = 0.f;
    #pragma unroll
    for (int mt = 0; mt < 2; mt++)
      #pragma unroll
      for (int r = 0; r < 4; r++) {
        const float v = acc[mt][nt][r] + b;
        Out[(m0 + mt*16 + lg*4 + r)*D_ + nt*16 + lr] = v;
        if (STATS) { s += v; q += v*v; }
      }
    if (STATS) {
      s += __shfl_xor(s, 16); s += __shfl_xor(s, 32);
      q += __shfl_xor(q, 16); q += __shfl_xor(q, 32);
      if (lg == 0) {
        lbs[w*128 + nt*16 + lr] = s;
        lbq[w*128 + nt*16 + lr] = q;
      }
    }
  }
  if (STATS) {
    __syncthreads();
    if (tid < 128) {
      const float ss = lbs[tid] + lbs[128 + tid] + lbs[256 + tid] + lbs[384 + tid];
      const float qq = lbq[tid] + lbq[128 + tid] + lbq[256 + tid] + lbq[384 + tid];
      psum[(size_t)blockIdx.x*128 + tid] = ss;
      psq [(size_t)blockIdx.x*128 + tid] = qq;
    }
  }
}

// ---------------------------------------------------------------------------
// Fallback BN stats + final stages
// ---------------------------------------------------------------------------
__global__ __launch_bounds__(256) void k_bnstats(
    const float* __restrict__ g, float* __restrict__ psum, float* __restrict__ psq)
{
  const int tid = threadIdx.x;
  const int c4 = (tid & 31) * 4, sub = tid >> 5;
  const size_t r0 = (size_t)blockIdx.x * BNROWS_FB;
  float4 s = make_float4(0.f,0.f,0.f,0.f), q = make_float4(0.f,0.f,0.f,0.f);
  for (int i = sub; i < BNROWS_FB; i += 8) {
    const float4 x = *(const float4*)(g + (r0 + i)*D_ + c4);
    s.x += x.x; s.y += x.y; s.z += x.z; s.w += x.w;
    q.x += x.x*x.x; q.y += x.y*x.y; q.z += x.z*x.z; q.w += x.w*x.w;
  }
  __shared__ float ls[8*128], lq[8*128];
  *(float4*)&ls[sub*128 + c4] = s;
  *(float4*)&lq[sub*128 + c4] = q;
  __syncthreads();
  if (tid < 128) {
    float ss = 0.f, qq = 0.f;
    #pragma unroll
    for (int k = 0; k < 8; k++) { ss += ls[k*128 + tid]; qq += lq[k*128 + tid]; }
    psum[(size_t)blockIdx.x*128 + tid] = ss;
    psq [(size_t)blockIdx.x*128 + tid] = qq;
  }
}

__global__ __launch_bounds__(1024) void k_bnfinal(
    const float* __restrict__ psum, const float* __restrict__ psq, int nblk,
    float* __restrict__ meanv, float* __restrict__ invstdv)
{
  const int tid = threadIdx.x;
  const int sub = tid >> 7, ch = tid & 127;
  float s = 0.f, q = 0.f;
  for (int i = sub; i < nblk; i += 8) {
    s += psum[(size_t)i*128 + ch];
    q += psq [(size_t)i*128 + ch];
  }
  __shared__ float ls[8*128], lq[8*128];
  ls[sub*128 + ch] = s; lq[sub*128 + ch] = q;
  __syncthreads();
  if (tid < 128) {
    float ss = 0.f, qq = 0.f;
    #pragma unroll
    for (int k = 0; k < 8; k++) { ss += ls[k*128 + tid]; qq += lq[k*128 + tid]; }
    const float mean = ss / (float)MROWS;
    const float var  = qq / (float)MROWS - mean*mean;
    meanv[tid] = mean;
    invstdv[tid] = rsqrtf(var + EPS_);
  }
}

__global__ __launch_bounds__(256) void k_final(
    float* __restrict__ g,
    const unsigned short* __restrict__ gcn, const unsigned short* __restrict__ attn,
    const float* __restrict__ meanv, const float* __restrict__ invstdv,
    const float* __restrict__ gamma, const float* __restrict__ beta)
{
  const size_t tot4 = SELEMS >> 2;
  for (size_t i4 = (size_t)blockIdx.x*blockDim.x + threadIdx.x; i4 < tot4;
       i4 += (size_t)gridDim.x*blockDim.x) {
    const int c4 = (int)(i4 & 31) * 4;
    const float4 gv = ((const float4*)g)[i4];
    const ushort4 gc = ((const ushort4*)gcn)[i4];
    const ushort4 at = ((const ushort4*)attn)[i4];
    const float4 m4 = *(const float4*)(meanv + c4);
    const float4 s4 = *(const float4*)(invstdv + c4);
    const float4 ga = *(const float4*)(gamma + c4);
    const float4 be = *(const float4*)(beta + c4);
    float4 outv;
    { const float y = (gv.x - m4.x)*s4.x*ga.x + be.x;
      const float z = 1.f/(1.f + __expf(-y));
      outv.x = z*bfu2f(gc.x) + (1.f - z)*bfu2f(at.x); }
    { const float y = (gv.y - m4.y)*s4.y*ga.y + be.y;
      const float z = 1.f/(1.f + __expf(-y));
      outv.y = z*bfu2f(gc.y) + (1.f - z)*bfu2f(at.y); }
    { const float y = (gv.z - m4.z)*s4.z*ga.z + be.z;
      const float z = 1.f/(1.f + __expf(-y));
      outv.z = z*bfu2f(gc.z) + (1.f - z)*bfu2f(at.z); }
    { const float y = (gv.w - m4.w)*s4.w*ga.w + be.w;
      const float z = 1.f/(1.f + __expf(-y));
      outv.w = z*bfu2f(gc.w) + (1.f - z)*bfu2f(at.w); }
    ((float4*)g)[i4] = outv;
  }
}

// ---------------------------------------------------------------------------
extern "C" void kernel_launch(void* const* d_in, const int* in_sizes, int n_in,
                              void* d_out, int out_size, void* d_ws, size_t ws_size,
                              hipStream_t stream)
{
  (void)in_sizes; (void)n_in; (void)out_size;
  const float* hidden = (const float*)d_in[0];
  const float* matrix = (const float*)d_in[1];
  const float* Wq   = (const float*)d_in[2];  const float* bq    = (const float*)d_in[3];
  const float* Wk   = (const float*)d_in[4];  const float* bk    = (const float*)d_in[5];
  const float* Wv   = (const float*)d_in[6];  const float* bv    = (const float*)d_in[7];
  const float* Wo   = (const float*)d_in[8];  const float* bo    = (const float*)d_in[9];
  const float* Wgcn = (const float*)d_in[10]; const float* bgcn  = (const float*)d_in[11];
  const float* Wgate= (const float*)d_in[12]; const float* bgate = (const float*)d_in[13];
  const float* gamma= (const float*)d_in[14]; const float* beta  = (const float*)d_in[15];
  float* out = (float*)d_out;

  // ws: weights bf16 | X1 bf16[SELEMS] | X2 bf16[SELEMS] | psum | psq | mean | invstd
  unsigned short* WB = (unsigned short*)d_ws;
  unsigned short* Wqb    = WB;
  unsigned short* Wkb    = WB + 16384;
  unsigned short* Wvb    = WB + 32768;
  unsigned short* Wob    = WB + 49152;
  unsigned short* Wgcnb  = WB + 65536;
  unsigned short* Wgateb = WB + 81920;
  unsigned short* X1     = WB + 114688;
  unsigned short* X2     = X1 + SELEMS;
  float* psum    = (float*)(X2 + SELEMS);

  const size_t base_bytes = (size_t)(WB + 114688 - (unsigned short*)d_ws)*2
                          + 2*SELEMS*2;
  const size_t fused_bytes = base_bytes + ((size_t)NBLK_FUSED*128*2 + 256)*4;
  const bool fused = (ws_size >= fused_bytes);
  const int nblk = fused ? NBLK_FUSED : NBLK_FB;
  float* psq     = psum + (size_t)nblk*128;
  float* meanv   = psq  + (size_t)nblk*128;
  float* invstdv = meanv + 128;

  k_wcast<<<112, 256, 0, stream>>>(Wq, Wk, Wv, Wo, Wgcn, Wgate, WB);
  k_gcn2 <<<dim3(2, B_*T_), 256, 0, stream>>>(hidden, matrix, Wgcnb, bgcn, X2);
  k_attn3<<<B_*N_, 256, 0, stream>>>(hidden, Wqb, Wkb, Wvb, Wob,
                                     bq, bk, bv, bo, X1);
  if (fused) {
    k_gate<true><<<MROWS/128, 256, 0, stream>>>(X2, X1, Wgateb, bgate, out, psum, psq);
  } else {
    k_gate<false><<<MROWS/128, 256, 0, stream>>>(X2, X1, Wgateb, bgate, out, psum, psq);
    k_bnstats<<<NBLK_FB, 256, 0, stream>>>(out, psum, psq);
  }
  k_bnfinal<<<1, 1024, 0, stream>>>(psum, psq, nblk, meanv, invstdv);
  k_final<<<2048, 256, 0, stream>>>(out, X2, X1, meanv, invstdv, gamma, beta);
}

// Round 8
// 750.861 us; speedup vs baseline: 2.7347x; 1.0862x over previous
//
#include <hip/hip_runtime.h>

#define B_ 64
#define N_ 207
#define T_ 24
#define D_ 128
#define H_ 8
#define MROWS (B_*N_*T_)             // 317952 = 128*2484
#define SELEMS ((size_t)MROWS * D_)  // 40697856
#define NBLK_FB 768
#define BNROWS_FB 414
#define NBLK_FUSED (MROWS/128)       // 2484 gate tiles
#define EPS_ 1e-5f

typedef __attribute__((ext_vector_type(8))) short s16x8;   // 8 bf16 (4 VGPR)
typedef __attribute__((ext_vector_type(4))) float f32x4;   // MFMA acc

#define MFMA16(a,b,c) __builtin_amdgcn_mfma_f32_16x16x32_bf16(a,b,c,0,0,0)

__device__ __forceinline__ float bfu2f(unsigned short u) {
  return __uint_as_float(((unsigned int)u) << 16);
}
__device__ __forceinline__ unsigned short f2bfu(float f) {
  unsigned int x = __float_as_uint(f);
  return (unsigned short)((x + 0x7fffu + ((x >> 16) & 1u)) >> 16);  // RNE
}
__device__ __forceinline__ unsigned int packbf2(float lo, float hi) {
  return (unsigned int)f2bfu(lo) | ((unsigned int)f2bfu(hi) << 16);
}

// ---------------------------------------------------------------------------
// Weight cast: Wq|Wk|Wv|Wo|Wgcn (128x128 each) | Wgate (128x256) -> bf16
// ---------------------------------------------------------------------------
__global__ __launch_bounds__(256) void k_wcast(
    const float* __restrict__ Wq, const float* __restrict__ Wk,
    const float* __restrict__ Wv, const float* __restrict__ Wo,
    const float* __restrict__ Wgcn, const float* __restrict__ Wgate,
    unsigned short* __restrict__ out)
{
  const int idx4 = (blockIdx.x * 256 + threadIdx.x) * 4;
  if (idx4 >= 114688) return;
  const float* src; int off;
  if      (idx4 < 16384) { src = Wq;    off = idx4; }
  else if (idx4 < 32768) { src = Wk;    off = idx4 - 16384; }
  else if (idx4 < 49152) { src = Wv;    off = idx4 - 32768; }
  else if (idx4 < 65536) { src = Wo;    off = idx4 - 49152; }
  else if (idx4 < 81920) { src = Wgcn;  off = idx4 - 65536; }
  else                   { src = Wgate; off = idx4 - 81920; }
  const float4 v = *(const float4*)(src + off);
  ushort4 u;
  u.x = f2bfu(v.x); u.y = f2bfu(v.y); u.z = f2bfu(v.z); u.w = f2bfu(v.w);
  *(ushort4*)(out + idx4) = u;
}

// ---------------------------------------------------------------------------
// GCN chunk loader: masked global->reg for matrix/hidden 32-n chunk `ch`.
// ---------------------------------------------------------------------------
__device__ __forceinline__ void gcn_load(
    const float* __restrict__ mbase, const float* __restrict__ hbase,
    int m0, int nn, int cb, int ch,
    float va[8], float vb[8], float ha[8], float hb[8])
{
  const int n_r0 = ch*32 + nn, n_r1 = n_r0 + 1;
  const bool rv0 = (n_r0 < N_), rv1 = (n_r1 < N_);
  const size_t nc0 = (size_t)(rv0 ? n_r0 : 0);
  const size_t nc1 = (size_t)(rv1 ? n_r1 : 0);
  {
    const float* r0 = mbase + nc0*N_ + m0 + cb;
    const float* r1 = mbase + nc1*N_ + m0 + cb;
    #pragma unroll
    for (int j = 0; j < 2; ++j) {
      const int mg = m0 + cb + j*4;
      if (mg + 3 < N_) {
        const float4 x0 = *(const float4*)(r0 + j*4);
        const float4 x1 = *(const float4*)(r1 + j*4);
        va[j*4+0]=x0.x; va[j*4+1]=x0.y; va[j*4+2]=x0.z; va[j*4+3]=x0.w;
        vb[j*4+0]=x1.x; vb[j*4+1]=x1.y; vb[j*4+2]=x1.z; vb[j*4+3]=x1.w;
      } else {
        #pragma unroll
        for (int e = 0; e < 4; ++e) {
          const bool ok = (mg + e) < N_;
          va[j*4+e] = ok ? r0[j*4+e] : 0.f;
          vb[j*4+e] = ok ? r1[j*4+e] : 0.f;
        }
      }
    }
    #pragma unroll
    for (int e = 0; e < 8; ++e) {
      if (!rv0) va[e] = 0.f;
      if (!rv1) vb[e] = 0.f;
    }
  }
  {
    const float* r0 = hbase + nc0*(T_*D_) + cb;
    const float* r1 = hbase + nc1*(T_*D_) + cb;
    const float4 x0a = *(const float4*)(r0);
    const float4 x0b = *(const float4*)(r0 + 4);
    const float4 x1a = *(const float4*)(r1);
    const float4 x1b = *(const float4*)(r1 + 4);
    ha[0]=x0a.x; ha[1]=x0a.y; ha[2]=x0a.z; ha[3]=x0a.w;
    ha[4]=x0b.x; ha[5]=x0b.y; ha[6]=x0b.z; ha[7]=x0b.w;
    hb[0]=x1a.x; hb[1]=x1a.y; hb[2]=x1a.z; hb[3]=x1a.w;
    hb[4]=x1b.x; hb[5]=x1b.y; hb[6]=x1b.z; hb[7]=x1b.w;
    #pragma unroll
    for (int e = 0; e < 8; ++e) {
      if (!rv0) ha[e] = 0.f;
      if (!rv1) hb[e] = 0.f;
    }
  }
}

// ---------------------------------------------------------------------------
// Fused GCN branch (MFMA, pipelined).
// ---------------------------------------------------------------------------
__global__ __launch_bounds__(256) void k_gcn2(
    const float* __restrict__ hidden, const float* __restrict__ matrix,
    const unsigned short* __restrict__ Wgcnb, const float* __restrict__ bgcn,
    unsigned short* __restrict__ gcn)
{
  __shared__ __align__(16) unsigned char smem[40960];
  unsigned short* GsAll = (unsigned short*)smem;

  const int tid = threadIdx.x;
  const int w = tid >> 6, l = tid & 63;
  const int lr = l & 15, lg = l >> 4;
  const int m0 = blockIdx.x * 128;
  const int by = (int)blockIdx.y;
  const int b = by / T_, t = by % T_;

  const int nn = (tid & 15) * 2;
  const int cb = (tid >> 4) * 8;

  const float* mbase = matrix + (size_t)(b*T_ + t)*N_*N_;
  const float* hbase = hidden + (size_t)b*N_*T_*D_ + (size_t)t*D_;

  f32x4 acc1[2][8];
  #pragma unroll
  for (int mt = 0; mt < 2; mt++)
    #pragma unroll
    for (int nt = 0; nt < 8; nt++)
      #pragma unroll
      for (int e = 0; e < 4; e++) acc1[mt][nt][e] = 0.f;

  float va[8], vb[8], ha[8], hb[8];
  gcn_load(mbase, hbase, m0, nn, cb, 0, va, vb, ha, hb);

  #pragma unroll
  for (int ch = 0; ch < 7; ++ch) {
    unsigned char* base = smem + ((ch & 1) ? 20480 : 0);
    unsigned int* M32 = (unsigned int*)base;
    unsigned int* H32 = (unsigned int*)(base + 10240);
    #pragma unroll
    for (int e = 0; e < 8; ++e)
      M32[(cb + e)*20 + (tid & 15)] = packbf2(va[e], vb[e]);
    #pragma unroll
    for (int e = 0; e < 8; ++e)
      H32[(cb + e)*20 + (tid & 15)] = packbf2(ha[e], hb[e]);
    if (ch < 6)
      gcn_load(mbase, hbase, m0, nn, cb, ch + 1, va, vb, ha, hb);
    __syncthreads();
    const unsigned short* M16 = (const unsigned short*)M32;
    const unsigned short* H16 = (const unsigned short*)H32;
    const s16x8 af0 = *(const s16x8*)(M16 + (size_t)(w*32 +  0 + lr)*40 + lg*8);
    const s16x8 af1 = *(const s16x8*)(M16 + (size_t)(w*32 + 16 + lr)*40 + lg*8);
    #pragma unroll
    for (int nt = 0; nt < 8; ++nt) {
      const s16x8 bf = *(const s16x8*)(H16 + (size_t)(nt*16 + lr)*40 + lg*8);
      acc1[0][nt] = MFMA16(af0, bf, acc1[0][nt]);
      acc1[1][nt] = MFMA16(af1, bf, acc1[1][nt]);
    }
  }

  __syncthreads();
  unsigned short* gs = GsAll + (size_t)w * (32*136);
  #pragma unroll
  for (int nt = 0; nt < 8; nt++)
    #pragma unroll
    for (int mt = 0; mt < 2; mt++)
      #pragma unroll
      for (int r = 0; r < 4; r++)
        gs[(mt*16 + lg*4 + r)*136 + nt*16 + lr] = f2bfu(acc1[mt][nt][r]);

  f32x4 acc2[2][8];
  #pragma unroll
  for (int mt = 0; mt < 2; mt++)
    #pragma unroll
    for (int nt = 0; nt < 8; nt++)
      #pragma unroll
      for (int e = 0; e < 4; e++) acc2[mt][nt][e] = 0.f;

  #pragma unroll
  for (int ks = 0; ks < 4; ++ks) {
    const s16x8 a0 = *(const s16x8*)(gs + (size_t)( 0 + lr)*136 + ks*32 + lg*8);
    const s16x8 a1 = *(const s16x8*)(gs + (size_t)(16 + lr)*136 + ks*32 + lg*8);
    #pragma unroll
    for (int nt = 0; nt < 8; ++nt) {
      const s16x8 bf = *(const s16x8*)(Wgcnb + (size_t)(nt*16 + lr)*D_ + ks*32 + lg*8);
      acc2[0][nt] = MFMA16(a0, bf, acc2[0][nt]);
      acc2[1][nt] = MFMA16(a1, bf, acc2[1][nt]);
    }
  }

  #pragma unroll
  for (int nt = 0; nt < 8; nt++) {
    const float bsc = bgcn[nt*16 + lr];
    #pragma unroll
    for (int mt = 0; mt < 2; mt++)
      #pragma unroll
      for (int r = 0; r < 4; r++)
        gs[(mt*16 + lg*4 + r)*136 + nt*16 + lr] = f2bfu(acc2[mt][nt][r] + bsc);
  }
  const size_t Obase = ((size_t)b*N_ + (m0 + w*32))*(size_t)(T_*D_) + (size_t)t*D_;
  #pragma unroll
  for (int p = 0; p < 8; p++) {
    const int c = p*64 + l;
    const int row = c >> 4, c8 = (c & 15) * 8;
    const int gm = m0 + w*32 + row;
    if (gm < N_) {
      const s16x8 v = *(const s16x8*)(gs + row*136 + c8);
      *(s16x8*)(gcn + Obase + (size_t)row*(T_*D_) + c8) = v;
    }
  }
}

// ---------------------------------------------------------------------------
// Fused attention v2: per (b,n) block, 4 waves. QK^T and PV on MFMA.
// Wave w owns output cols w*32..w*32+31 of Q/K/V and heads 2w, 2w+1:
// the whole QK->softmax->PV chain is wave-local (no barriers).
// ---------------------------------------------------------------------------
__global__ __launch_bounds__(256) void k_attn3(
    const float* __restrict__ hidden,
    const unsigned short* __restrict__ Wqb, const unsigned short* __restrict__ Wkb,
    const unsigned short* __restrict__ Wvb, const unsigned short* __restrict__ Wob,
    const float* __restrict__ bq, const float* __restrict__ bk,
    const float* __restrict__ bv, const float* __restrict__ bo,
    unsigned short* __restrict__ attnO)
{
  __shared__ __align__(16) unsigned short Xs[32*136];   // X, later ctx
  __shared__ __align__(16) unsigned short Qs[32*136];   // Q, later Wo out
  __shared__ __align__(16) unsigned short Ks[32*136];
  __shared__ __align__(16) unsigned short Vt[128*40];   // V transposed [d][t]
  __shared__ __align__(16) unsigned short Ps[4][32*40]; // per-wave P (A-layout)
  const int tid = threadIdx.x;
  const int w = tid >> 6, l = tid & 63;
  const int lr = l & 15, lg = l >> 4;
  const size_t bn = blockIdx.x;
  const float* X = hidden + bn * (size_t)(T_*D_);

  // stage X -> Xs (bf16), rows 24..31 zero
  for (int i = tid; i < 32*16; i += 256) {
    const int row = i >> 4, g8 = (i & 15) * 8;
    s16x8 v;
    if (row < T_) {
      const float4 a  = *(const float4*)(X + (size_t)row*D_ + g8);
      const float4 b2 = *(const float4*)(X + (size_t)row*D_ + g8 + 4);
      v[0]=(short)f2bfu(a.x);  v[1]=(short)f2bfu(a.y);
      v[2]=(short)f2bfu(a.z);  v[3]=(short)f2bfu(a.w);
      v[4]=(short)f2bfu(b2.x); v[5]=(short)f2bfu(b2.y);
      v[6]=(short)f2bfu(b2.z); v[7]=(short)f2bfu(b2.w);
    } else {
      #pragma unroll
      for (int e = 0; e < 8; e++) v[e] = 0;
    }
    *(s16x8*)&Xs[row*136 + g8] = v;
  }
  __syncthreads();

  // A-frags of X (all waves read all of Xs here; barrier after)
  s16x8 af[2][4];
  #pragma unroll
  for (int mt = 0; mt < 2; mt++)
    #pragma unroll
    for (int ks = 0; ks < 4; ks++)
      af[mt][ks] = *(const s16x8*)&Xs[(mt*16 + lr)*136 + ks*32 + lg*8];
  __syncthreads();   // after this, Xs is free for ctx writes

  // ---- Q/K/V projections: wave w computes cols 32w..32w+31 (wave-local use)
  const unsigned short* Wp[3] = {Wqb, Wkb, Wvb};
  const float*          bp[3] = {bq, bk, bv};
  #pragma unroll
  for (int o = 0; o < 3; o++) {
    f32x4 acc[2][2];
    #pragma unroll
    for (int mt = 0; mt < 2; mt++)
      #pragma unroll
      for (int nt = 0; nt < 2; nt++)
        #pragma unroll
        for (int e = 0; e < 4; e++) acc[mt][nt][e] = 0.f;
    #pragma unroll
    for (int ks = 0; ks < 4; ks++) {
      #pragma unroll
      for (int nt = 0; nt < 2; nt++) {
        const s16x8 bf = *(const s16x8*)(Wp[o] + (size_t)(w*32 + nt*16 + lr)*D_ + ks*32 + lg*8);
        acc[0][nt] = MFMA16(af[0][ks], bf, acc[0][nt]);
        acc[1][nt] = MFMA16(af[1][ks], bf, acc[1][nt]);
      }
    }
    #pragma unroll
    for (int nt = 0; nt < 2; nt++) {
      const float bb = bp[o][w*32 + nt*16 + lr];
      #pragma unroll
      for (int mt = 0; mt < 2; mt++)
        #pragma unroll
        for (int r = 0; r < 4; r++) {
          const unsigned short hv = f2bfu(acc[mt][nt][r] + bb);
          const int trow = mt*16 + lg*4 + r;          // t index
          const int dcol = w*32 + nt*16 + lr;          // output dim
          if (o == 0)      Qs[trow*136 + dcol] = hv;
          else if (o == 1) Ks[trow*136 + dcol] = hv;
          else             Vt[dcol*40 + trow] = hv;    // transposed
        }
    }
  }

  // ---- per-head attention, fully wave-local (LDS cols/rows owned by wave w)
  unsigned short* Pw = Ps[w];
  #pragma unroll
  for (int hi = 0; hi < 2; hi++) {
    const int hh = 2*w + hi;
    // QK^T: K-dim 16 real (lanes lg<2), zero pad lanes lg>=2
    s16x8 zv;
    #pragma unroll
    for (int e = 0; e < 8; e++) zv[e] = 0;
    s16x8 aq[2], bkf[2];
    #pragma unroll
    for (int mt = 0; mt < 2; mt++) {
      s16x8 tv = zv;
      if (lg < 2) tv = *(const s16x8*)&Qs[(mt*16 + lr)*136 + hh*16 + lg*8];
      aq[mt] = tv;
    }
    #pragma unroll
    for (int nt = 0; nt < 2; nt++) {
      s16x8 tv = zv;
      if (lg < 2) tv = *(const s16x8*)&Ks[(nt*16 + lr)*136 + hh*16 + lg*8];
      bkf[nt] = tv;
    }
    f32x4 accS[2][2];
    #pragma unroll
    for (int mt = 0; mt < 2; mt++)
      #pragma unroll
      for (int nt = 0; nt < 2; nt++) {
        f32x4 z4; z4[0]=0.f; z4[1]=0.f; z4[2]=0.f; z4[3]=0.f;
        accS[mt][nt] = MFMA16(aq[mt], bkf[nt], z4);
      }
    // softmax per row t (C layout: row = mt*16+lg*4+r, col s = nt*16+lr)
    #pragma unroll
    for (int mt = 0; mt < 2; mt++) {
      #pragma unroll
      for (int r = 0; r < 4; r++) {
        const int t = mt*16 + lg*4 + r;
        const bool m0 = (lr <= t), m1 = (16 + lr <= t);
        float e0 = m0 ? __expf(0.25f * accS[mt][0][r]) : 0.f;
        float e1 = m1 ? __expf(0.25f * accS[mt][1][r]) : 0.f;
        float den = e0 + e1;
        den += __shfl_xor(den, 1);
        den += __shfl_xor(den, 2);
        den += __shfl_xor(den, 4);
        den += __shfl_xor(den, 8);
        const float rd = 1.f / den;
        Pw[t*40 + lr]      = f2bfu(e0 * rd);
        Pw[t*40 + 16 + lr] = f2bfu(e1 * rd);
      }
    }
    // PV: ctx[t, d] = sum_s P[t,s] V[s,d]; K=32 (cols >=24 are zeros)
    s16x8 ap[2];
    #pragma unroll
    for (int mt = 0; mt < 2; mt++)
      ap[mt] = *(const s16x8*)&Pw[(mt*16 + lr)*40 + lg*8];
    const s16x8 bvf = *(const s16x8*)&Vt[(hh*16 + lr)*40 + lg*8];
    f32x4 accP[2];
    #pragma unroll
    for (int mt = 0; mt < 2; mt++) {
      f32x4 z4; z4[0]=0.f; z4[1]=0.f; z4[2]=0.f; z4[3]=0.f;
      accP[mt] = MFMA16(ap[mt], bvf, z4);
    }
    // ctx -> Xs (rows t<24 only; rows>=24 keep X's zero padding)
    #pragma unroll
    for (int mt = 0; mt < 2; mt++)
      #pragma unroll
      for (int r = 0; r < 4; r++) {
        const int t = mt*16 + lg*4 + r;
        if (t < T_) Xs[t*136 + hh*16 + lr] = f2bfu(accP[mt][r]);
      }
  }
  __syncthreads();

  // ---- Wo GEMM: A = ctx (Xs), out -> Qs, cooperative store rows<24
  s16x8 cf[2][4];
  #pragma unroll
  for (int mt = 0; mt < 2; mt++)
    #pragma unroll
    for (int ks = 0; ks < 4; ks++)
      cf[mt][ks] = *(const s16x8*)&Xs[(mt*16 + lr)*136 + ks*32 + lg*8];
  f32x4 acc2[2][2];
  #pragma unroll
  for (int mt = 0; mt < 2; mt++)
    #pragma unroll
    for (int nt = 0; nt < 2; nt++)
      #pragma unroll
      for (int e = 0; e < 4; e++) acc2[mt][nt][e] = 0.f;
  #pragma unroll
  for (int ks = 0; ks < 4; ks++) {
    #pragma unroll
    for (int nt = 0; nt < 2; nt++) {
      const s16x8 bf = *(const s16x8*)(Wob + (size_t)(w*32 + nt*16 + lr)*D_ + ks*32 + lg*8);
      acc2[0][nt] = MFMA16(cf[0][ks], bf, acc2[0][nt]);
      acc2[1][nt] = MFMA16(cf[1][ks], bf, acc2[1][nt]);
    }
  }
  #pragma unroll
  for (int nt = 0; nt < 2; nt++) {
    const float bb = bo[w*32 + nt*16 + lr];
    #pragma unroll
    for (int mt = 0; mt < 2; mt++)
      #pragma unroll
      for (int r = 0; r < 4; r++)
        Qs[(mt*16 + lg*4 + r)*136 + w*32 + nt*16 + lr] =
            f2bfu(acc2[mt][nt][r] + bb);
  }
  __syncthreads();
  unsigned short* O = attnO + bn * (size_t)(T_*D_);
  for (int i = tid; i < 24*16; i += 256) {
    const int row = i >> 4, g8 = (i & 15) * 8;
    *(s16x8*)(O + (size_t)row*D_ + g8) = *(const s16x8*)&Qs[row*136 + g8];
  }
}

// ---------------------------------------------------------------------------
// Gate GEMM + optional fused BN partial stats.
// ---------------------------------------------------------------------------
template<bool STATS>
__global__ __launch_bounds__(256) void k_gate(
    const unsigned short* __restrict__ A0, const unsigned short* __restrict__ A1,
    const unsigned short* __restrict__ Wb, const float* __restrict__ bias,
    float* __restrict__ Out, float* __restrict__ psum, float* __restrict__ psq)
{
  __shared__ float lbs[4*128], lbq[4*128];
  const int tid = threadIdx.x;
  const int w = tid >> 6, l = tid & 63;
  const int lr = l & 15, lg = l >> 4;
  const size_t m0 = (size_t)blockIdx.x * 128 + w * 32;

  f32x4 acc[2][8];
  #pragma unroll
  for (int mt = 0; mt < 2; mt++)
    #pragma unroll
    for (int nt = 0; nt < 8; nt++)
      #pragma unroll
      for (int e = 0; e < 4; e++) acc[mt][nt][e] = 0.f;

  #pragma unroll
  for (int ks = 0; ks < 8; ks++) {
    const unsigned short* Asrc = (ks >= 4) ? A1 : A0;
    const int kk = (ks >= 4) ? ks - 4 : ks;
    const s16x8 a0 = *(const s16x8*)(Asrc + (m0 +  0 + lr)*D_ + kk*32 + lg*8);
    const s16x8 a1 = *(const s16x8*)(Asrc + (m0 + 16 + lr)*D_ + kk*32 + lg*8);
    #pragma unroll
    for (int nt = 0; nt < 8; nt++) {
      const s16x8 bf = *(const s16x8*)(Wb + (size_t)(nt*16 + lr)*256 + ks*32 + lg*8);
      acc[0][nt] = MFMA16(a0, bf, acc[0][nt]);
      acc[1][nt] = MFMA16(a1, bf, acc[1][nt]);
    }
  }

  #pragma unroll
  for (int nt = 0; nt < 8; nt++) {
    const float b = bias[nt*16 + lr];
    float s = 0.f, q = 0.f;
    #pragma unroll
    for (int mt = 0; mt < 2; mt++)
      #pragma unroll
      for (int r = 0; r < 4; r++) {
        const float v = acc[mt][nt][r] + b;
        Out[(m0 + mt*16 + lg*4 + r)*D_ + nt*16 + lr] = v;
        if (STATS) { s += v; q += v*v; }
      }
    if (STATS) {
      s += __shfl_xor(s, 16); s += __shfl_xor(s, 32);
      q += __shfl_xor(q, 16); q += __shfl_xor(q, 32);
      if (lg == 0) {
        lbs[w*128 + nt*16 + lr] = s;
        lbq[w*128 + nt*16 + lr] = q;
      }
    }
  }
  if (STATS) {
    __syncthreads();
    if (tid < 128) {
      const float ss = lbs[tid] + lbs[128 + tid] + lbs[256 + tid] + lbs[384 + tid];
      const float qq = lbq[tid] + lbq[128 + tid] + lbq[256 + tid] + lbq[384 + tid];
      psum[(size_t)blockIdx.x*128 + tid] = ss;
      psq [(size_t)blockIdx.x*128 + tid] = qq;
    }
  }
}

// ---------------------------------------------------------------------------
// Fallback BN stats + final stages
// ---------------------------------------------------------------------------
__global__ __launch_bounds__(256) void k_bnstats(
    const float* __restrict__ g, float* __restrict__ psum, float* __restrict__ psq)
{
  const int tid = threadIdx.x;
  const int c4 = (tid & 31) * 4, sub = tid >> 5;
  const size_t r0 = (size_t)blockIdx.x * BNROWS_FB;
  float4 s = make_float4(0.f,0.f,0.f,0.f), q = make_float4(0.f,0.f,0.f,0.f);
  for (int i = sub; i < BNROWS_FB; i += 8) {
    const float4 x = *(const float4*)(g + (r0 + i)*D_ + c4);
    s.x += x.x; s.y += x.y; s.z += x.z; s.w += x.w;
    q.x += x.x*x.x; q.y += x.y*x.y; q.z += x.z*x.z; q.w += x.w*x.w;
  }
  __shared__ float ls[8*128], lq[8*128];
  *(float4*)&ls[sub*128 + c4] = s;
  *(float4*)&lq[sub*128 + c4] = q;
  __syncthreads();
  if (tid < 128) {
    float ss = 0.f, qq = 0.f;
    #pragma unroll
    for (int k = 0; k < 8; k++) { ss += ls[k*128 + tid]; qq += lq[k*128 + tid]; }
    psum[(size_t)blockIdx.x*128 + tid] = ss;
    psq [(size_t)blockIdx.x*128 + tid] = qq;
  }
}

__global__ __launch_bounds__(1024) void k_bnfinal(
    const float* __restrict__ psum, const float* __restrict__ psq, int nblk,
    float* __restrict__ meanv, float* __restrict__ invstdv)
{
  const int tid = threadIdx.x;
  const int sub = tid >> 7, ch = tid & 127;
  float s = 0.f, q = 0.f;
  for (int i = sub; i < nblk; i += 8) {
    s += psum[(size_t)i*128 + ch];
    q += psq [(size_t)i*128 + ch];
  }
  __shared__ float ls[8*128], lq[8*128];
  ls[sub*128 + ch] = s; lq[sub*128 + ch] = q;
  __syncthreads();
  if (tid < 128) {
    float ss = 0.f, qq = 0.f;
    #pragma unroll
    for (int k = 0; k < 8; k++) { ss += ls[k*128 + tid]; qq += lq[k*128 + tid]; }
    const float mean = ss / (float)MROWS;
    const float var  = qq / (float)MROWS - mean*mean;
    meanv[tid] = mean;
    invstdv[tid] = rsqrtf(var + EPS_);
  }
}

__global__ __launch_bounds__(256) void k_final(
    float* __restrict__ g,
    const unsigned short* __restrict__ gcn, const unsigned short* __restrict__ attn,
    const float* __restrict__ meanv, const float* __restrict__ invstdv,
    const float* __restrict__ gamma, const float* __restrict__ beta)
{
  const size_t tot4 = SELEMS >> 2;
  for (size_t i4 = (size_t)blockIdx.x*blockDim.x + threadIdx.x; i4 < tot4;
       i4 += (size_t)gridDim.x*blockDim.x) {
    const int c4 = (int)(i4 & 31) * 4;
    const float4 gv = ((const float4*)g)[i4];
    const ushort4 gc = ((const ushort4*)gcn)[i4];
    const ushort4 at = ((const ushort4*)attn)[i4];
    const float4 m4 = *(const float4*)(meanv + c4);
    const float4 s4 = *(const float4*)(invstdv + c4);
    const float4 ga = *(const float4*)(gamma + c4);
    const float4 be = *(const float4*)(beta + c4);
    float4 outv;
    { const float y = (gv.x - m4.x)*s4.x*ga.x + be.x;
      const float z = 1.f/(1.f + __expf(-y));
      outv.x = z*bfu2f(gc.x) + (1.f - z)*bfu2f(at.x); }
    { const float y = (gv.y - m4.y)*s4.y*ga.y + be.y;
      const float z = 1.f/(1.f + __expf(-y));
      outv.y = z*bfu2f(gc.y) + (1.f - z)*bfu2f(at.y); }
    { const float y = (gv.z - m4.z)*s4.z*ga.z + be.z;
      const float z = 1.f/(1.f + __expf(-y));
      outv.z = z*bfu2f(gc.z) + (1.f - z)*bfu2f(at.z); }
    { const float y = (gv.w - m4.w)*s4.w*ga.w + be.w;
      const float z = 1.f/(1.f + __expf(-y));
      outv.w = z*bfu2f(gc.w) + (1.f - z)*bfu2f(at.w); }
    ((float4*)g)[i4] = outv;
  }
}

// ---------------------------------------------------------------------------
extern "C" void kernel_launch(void* const* d_in, const int* in_sizes, int n_in,
                              void* d_out, int out_size, void* d_ws, size_t ws_size,
                              hipStream_t stream)
{
  (void)in_sizes; (void)n_in; (void)out_size;
  const float* hidden = (const float*)d_in[0];
  const float* matrix = (const float*)d_in[1];
  const float* Wq   = (const float*)d_in[2];  const float* bq    = (const float*)d_in[3];
  const float* Wk   = (const float*)d_in[4];  const float* bk    = (const float*)d_in[5];
  const float* Wv   = (const float*)d_in[6];  const float* bv    = (const float*)d_in[7];
  const float* Wo   = (const float*)d_in[8];  const float* bo    = (const float*)d_in[9];
  const float* Wgcn = (const float*)d_in[10]; const float* bgcn  = (const float*)d_in[11];
  const float* Wgate= (const float*)d_in[12]; const float* bgate = (const float*)d_in[13];
  const float* gamma= (const float*)d_in[14]; const float* beta  = (const float*)d_in[15];
  float* out = (float*)d_out;

  unsigned short* WB = (unsigned short*)d_ws;
  unsigned short* Wqb    = WB;
  unsigned short* Wkb    = WB + 16384;
  unsigned short* Wvb    = WB + 32768;
  unsigned short* Wob    = WB + 49152;
  unsigned short* Wgcnb  = WB + 65536;
  unsigned short* Wgateb = WB + 81920;
  unsigned short* X1     = WB + 114688;
  unsigned short* X2     = X1 + SELEMS;
  float* psum    = (float*)(X2 + SELEMS);

  const size_t base_bytes = (size_t)(WB + 114688 - (unsigned short*)d_ws)*2
                          + 2*SELEMS*2;
  const size_t fused_bytes = base_bytes + ((size_t)NBLK_FUSED*128*2 + 256)*4;
  const bool fused = (ws_size >= fused_bytes);
  const int nblk = fused ? NBLK_FUSED : NBLK_FB;
  float* psq     = psum + (size_t)nblk*128;
  float* meanv   = psq  + (size_t)nblk*128;
  float* invstdv = meanv + 128;

  k_wcast<<<112, 256, 0, stream>>>(Wq, Wk, Wv, Wo, Wgcn, Wgate, WB);
  k_gcn2 <<<dim3(2, B_*T_), 256, 0, stream>>>(hidden, matrix, Wgcnb, bgcn, X2);
  k_attn3<<<B_*N_, 256, 0, stream>>>(hidden, Wqb, Wkb, Wvb, Wob,
                                     bq, bk, bv, bo, X1);
  if (fused) {
    k_gate<true><<<MROWS/128, 256, 0, stream>>>(X2, X1, Wgateb, bgate, out, psum, psq);
  } else {
    k_gate<false><<<MROWS/128, 256, 0, stream>>>(X2, X1, Wgateb, bgate, out, psum, psq);
    k_bnstats<<<NBLK_FB, 256, 0, stream>>>(out, psum, psq);
  }
  k_bnfinal<<<1, 1024, 0, stream>>>(psum, psq, nblk, meanv, invstdv);
  k_final<<<2048, 256, 0, stream>>>(out, X2, X1, meanv, invstdv, gamma, beta);
}